// Round 1
// baseline (788.641 us; speedup 1.0000x reference)
//
#include <hip/hip_runtime.h>

// Problem constants: B=2, N=4, C=256, H=W=128, J=2, heads=8, hd=32, T=1024
// ws layout (floats):
//  qll  524288 | yh0 6291456 | yh1 1572864 | kvll 2097152 | qb 2097152
//  kb 2097152 | vb 2097152 | ao 2097152 | mb 524288   => 19,398,656 floats (74 MB)

__global__ __launch_bounds__(256) void qdwt_kernel(const float* __restrict__ x,
    float* __restrict__ qll, float* __restrict__ yh0, float* __restrict__ yh1) {
  int idx = blockIdx.x * 256 + threadIdx.x;   // < 2*256*1024
  int bc = idx >> 10;
  int t  = idx & 1023;
  int i = t >> 5, j = t & 31;
  const float* xp = x + (size_t)bc * 16384;
  float r[4][4];
#pragma unroll
  for (int rr = 0; rr < 4; ++rr) {
    float4 v = *reinterpret_cast<const float4*>(xp + (4 * i + rr) * 128 + 4 * j);
    r[rr][0] = v.x; r[rr][1] = v.y; r[rr][2] = v.z; r[rr][3] = v.w;
  }
  float ll1[2][2];
  size_t b0 = (size_t)bc * 3 * 4096;
#pragma unroll
  for (int a = 0; a < 2; ++a)
#pragma unroll
    for (int b = 0; b < 2; ++b) {
      float x00 = r[2*a][2*b], x01 = r[2*a][2*b+1];
      float x10 = r[2*a+1][2*b], x11 = r[2*a+1][2*b+1];
      float ll = 0.5f * (x00 + x01 + x10 + x11);
      float lh = 0.5f * (x00 + x01 - x10 - x11);
      float hl = 0.5f * (x00 - x01 + x10 - x11);
      float hh = 0.5f * (x00 - x01 - x10 + x11);
      ll1[a][b] = ll;
      int pos = (2*i + a) * 64 + (2*j + b);
      yh0[b0 + pos]        = lh;
      yh0[b0 + 4096 + pos] = hl;
      yh0[b0 + 8192 + pos] = hh;
    }
  float x00 = ll1[0][0], x01 = ll1[0][1], x10 = ll1[1][0], x11 = ll1[1][1];
  float ll2 = 0.5f * (x00 + x01 + x10 + x11);
  float lh2 = 0.5f * (x00 + x01 - x10 - x11);
  float hl2 = 0.5f * (x00 - x01 + x10 - x11);
  float hh2 = 0.5f * (x00 - x01 - x10 + x11);
  qll[idx] = ll2;
  size_t b1 = (size_t)bc * 3 * 1024;
  yh1[b1 + t]        = lh2;
  yh1[b1 + 1024 + t] = hl2;
  yh1[b1 + 2048 + t] = hh2;
}

// kv: flat j = n*B + b reads key_value_multi[b, n]; output (j, C, 32, 32)
__global__ __launch_bounds__(256) void kvdwt_kernel(const float* __restrict__ kvm,
                                                    float* __restrict__ ll) {
  int idx = blockIdx.x * 256 + threadIdx.x;   // < 8*256*1024
  int bc = idx >> 10;      // j*256 + c
  int t  = idx & 1023;
  int i = t >> 5, j2 = t & 31;
  int jj = bc >> 8, c = bc & 255;
  int n = jj >> 1, b = jj & 1;
  const float* xp = kvm + ((size_t)(b * 4 + n) * 256 + c) * 16384;
  float s = 0.f;
#pragma unroll
  for (int rr = 0; rr < 4; ++rr) {
    float4 v = *reinterpret_cast<const float4*>(xp + (4 * i + rr) * 128 + 4 * j2);
    s += (v.x + v.y) + (v.z + v.w);
  }
  ll[idx] = 0.25f * s;
}

// Y[j][o][t] = sum_c W[o][c] * X[j % in_mod][c][t] + bias[o];  M=K=256, T=1024
__global__ __launch_bounds__(256) void conv1x1_kernel(const float* __restrict__ X,
    const float* __restrict__ Wm, const float* __restrict__ bias,
    float* __restrict__ Y, int in_mod) {
  int tx = threadIdx.x, ty = threadIdx.y;
  int t0 = blockIdx.x * 16, o0 = blockIdx.y * 16, j = blockIdx.z;
  const float* Xp = X + (size_t)(j % in_mod) * 262144;
  __shared__ float Wt[16][17];
  __shared__ float Xt[16][17];
  float acc = 0.f;
  for (int k0 = 0; k0 < 256; k0 += 16) {
    Wt[ty][tx] = Wm[(o0 + ty) * 256 + k0 + tx];
    Xt[ty][tx] = Xp[(size_t)(k0 + ty) * 1024 + t0 + tx];
    __syncthreads();
#pragma unroll
    for (int kk = 0; kk < 16; ++kk) acc += Wt[ty][kk] * Xt[kk][tx];
    __syncthreads();
  }
  Y[((size_t)j * 256 + o0 + ty) * 1024 + t0 + tx] = acc + bias[o0 + ty];
}

// flash attention: one thread per query row; 64 (j,h) pairs, T=1024, d=32
#define KTILE 16
__global__ __launch_bounds__(256) void attn_kernel(const float* __restrict__ qb,
    const float* __restrict__ kb, const float* __restrict__ vb,
    float* __restrict__ ob) {
  int gid = blockIdx.x;            // 256 blocks
  int jh  = gid >> 2;              // 0..63
  int t   = (gid & 3) * 256 + threadIdx.x;
  size_t base = (size_t)jh * 32768;  // (j*256 + h*32) * 1024
  const float* qp = qb + base;
  const float* kp = kb + base;
  const float* vp = vb + base;
  float Qr[32];
#pragma unroll
  for (int d = 0; d < 32; ++d) Qr[d] = qp[(size_t)d * 1024 + t] * 0.17677669529663687f;
  float m = -1e30f, l = 0.f;
  float acc[32];
#pragma unroll
  for (int d = 0; d < 32; ++d) acc[d] = 0.f;
  __shared__ float Kl[KTILE * 32];   // [tk][d]
  __shared__ float Vl[KTILE * 32];   // [tk][d]
  for (int tile = 0; tile < 1024 / KTILE; ++tile) {
    __syncthreads();
    for (int e = threadIdx.x; e < KTILE * 32; e += 256) {
      int d = e >> 4, tk = e & (KTILE - 1);       // read d-major from global
      Kl[tk * 32 + d] = kp[(size_t)d * 1024 + tile * KTILE + tk];
      Vl[tk * 32 + d] = vp[(size_t)d * 1024 + tile * KTILE + tk];
    }
    __syncthreads();
    float s[KTILE];
#pragma unroll
    for (int tk = 0; tk < KTILE; ++tk) {
      float acc_s = 0.f;
      const float4* kk4 = reinterpret_cast<const float4*>(&Kl[tk * 32]);
#pragma unroll
      for (int d4 = 0; d4 < 8; ++d4) {
        float4 kv = kk4[d4];
        acc_s += Qr[d4*4+0] * kv.x + Qr[d4*4+1] * kv.y + Qr[d4*4+2] * kv.z + Qr[d4*4+3] * kv.w;
      }
      s[tk] = acc_s;
    }
    float tmax = s[0];
#pragma unroll
    for (int tk = 1; tk < KTILE; ++tk) tmax = fmaxf(tmax, s[tk]);
    if (tmax > m) {
      float f = __expf(m - tmax);
      l *= f;
#pragma unroll
      for (int d = 0; d < 32; ++d) acc[d] *= f;
      m = tmax;
    }
#pragma unroll
    for (int tk = 0; tk < KTILE; ++tk) {
      float p = __expf(s[tk] - m);
      l += p;
      const float4* vv4 = reinterpret_cast<const float4*>(&Vl[tk * 32]);
#pragma unroll
      for (int d4 = 0; d4 < 8; ++d4) {
        float4 vv = vv4[d4];
        acc[d4*4+0] += p * vv.x; acc[d4*4+1] += p * vv.y;
        acc[d4*4+2] += p * vv.z; acc[d4*4+3] += p * vv.w;
      }
    }
  }
  float inv = 1.f / l;
#pragma unroll
  for (int d = 0; d < 32; ++d) ob[base + (size_t)d * 1024 + t] = acc[d] * inv;
}

// m[b'][c][t] = 0.25 * sum_{n'=0..3} outp[b'*4+n'][c][t]
__global__ __launch_bounds__(256) void mean4_kernel(const float* __restrict__ outp,
                                                    float* __restrict__ mb) {
  int idx = blockIdx.x * 256 + threadIdx.x;   // < 524288
  int bp = idx >> 18;
  int rem = idx & 262143;
  float s = 0.f;
#pragma unroll
  for (int n = 0; n < 4; ++n) s += outp[((size_t)(bp * 4 + n)) * 262144 + rem];
  mb[idx] = s * 0.25f;
}

// one inverse DWT level: ll (bc,hw,hw) + bands (bc,3,hw,hw) -> out (bc,2hw,2hw)
__global__ __launch_bounds__(256) void idwt_kernel(const float* __restrict__ ll,
    const float* __restrict__ bands, float* __restrict__ outp, int hw) {
  int idx = blockIdx.x * 256 + threadIdx.x;   // < 512*hw*hw
  int hw2 = hw * hw;
  int bc = idx / hw2;
  int t  = idx - bc * hw2;
  int i = t / hw, j = t - i * hw;
  float vll = ll[idx];
  size_t bb = (size_t)bc * 3 * hw2 + t;
  float lh = bands[bb], hl = bands[bb + hw2], hh = bands[bb + 2 * hw2];
  float a  = vll + lh, b2 = vll - lh;
  float c2 = hl + hh,  d2 = hl - hh;
  int W2 = 2 * hw;
  float2 row0 = make_float2(0.5f * (a + c2), 0.5f * (a - c2));
  float2 row1 = make_float2(0.5f * (b2 + d2), 0.5f * (b2 - d2));
  float* op = outp + (size_t)bc * W2 * W2;
  *reinterpret_cast<float2*>(op + (size_t)(2 * i) * W2 + 2 * j)     = row0;
  *reinterpret_cast<float2*>(op + (size_t)(2 * i + 1) * W2 + 2 * j) = row1;
}

// group stats: 64 groups (b*32+g), each 8 ch x 128 x 128 = 131072 contiguous floats
__global__ __launch_bounds__(256) void gn_stats_kernel(const float* __restrict__ pre,
                                                       float* __restrict__ stats) {
  int g = blockIdx.x;
  int tid = threadIdx.x;
  const float4* p = reinterpret_cast<const float4*>(pre + (size_t)g * 131072);
  float s = 0.f, s2 = 0.f;
  for (int e = tid; e < 32768; e += 256) {
    float4 v = p[e];
    s  += (v.x + v.y) + (v.z + v.w);
    s2 += (v.x * v.x + v.y * v.y) + (v.z * v.z + v.w * v.w);
  }
  __shared__ float ls[256], ls2[256];
  ls[tid] = s; ls2[tid] = s2;
  __syncthreads();
  for (int off = 128; off > 0; off >>= 1) {
    if (tid < off) { ls[tid] += ls[tid + off]; ls2[tid] += ls2[tid + off]; }
    __syncthreads();
  }
  if (tid == 0) {
    float mean = ls[0] * (1.f / 131072.f);
    float var  = ls2[0] * (1.f / 131072.f) - mean * mean;
    stats[g * 2]     = mean;
    stats[g * 2 + 1] = rsqrtf(var + 1e-5f);
  }
}

__global__ __launch_bounds__(256) void gn_apply_kernel(float* __restrict__ outp,
    const float* __restrict__ query, const float* __restrict__ stats,
    const float* __restrict__ gamma, const float* __restrict__ beta) {
  int idx = blockIdx.x * 256 + threadIdx.x;   // < 2097152 float4 units
  size_t e = (size_t)idx * 4;
  int c = (int)((e >> 14) & 255);
  int b = (int)(e >> 22);
  int g = b * 32 + (c >> 3);
  float mean = stats[g * 2], rstd = stats[g * 2 + 1];
  float ga = gamma[c], be = beta[c];
  float4 v = *reinterpret_cast<const float4*>(outp + e);
  float4 q = *reinterpret_cast<const float4*>(query + e);
  v.x = (v.x - mean) * rstd * ga + be + q.x;
  v.y = (v.y - mean) * rstd * ga + be + q.y;
  v.z = (v.z - mean) * rstd * ga + be + q.z;
  v.w = (v.w - mean) * rstd * ga + be + q.w;
  *reinterpret_cast<float4*>(outp + e) = v;
}

extern "C" void kernel_launch(void* const* d_in, const int* in_sizes, int n_in,
                              void* d_out, int out_size, void* d_ws, size_t ws_size,
                              hipStream_t stream) {
  const float* query = (const float*)d_in[0];
  const float* kvm   = (const float*)d_in[1];
  // d_in[2] = value_multi: unused by the reference
  const float* Wq = (const float*)d_in[3];
  const float* bq = (const float*)d_in[4];
  const float* Wk = (const float*)d_in[5];
  const float* bk = (const float*)d_in[6];
  const float* Wv = (const float*)d_in[7];
  const float* bv = (const float*)d_in[8];
  const float* Wp = (const float*)d_in[9];
  const float* bp = (const float*)d_in[10];
  const float* gamma = (const float*)d_in[11];
  const float* beta  = (const float*)d_in[12];
  float* out = (float*)d_out;
  float* ws  = (float*)d_ws;

  if (ws_size < (size_t)19398656 * 4) return;  // insufficient scratch

  float* qll  = ws;                   // 524288
  float* yh0  = qll  + 524288;        // 6291456
  float* yh1  = yh0  + 6291456;       // 1572864
  float* kvll = yh1  + 1572864;       // 2097152
  float* qb   = kvll + 2097152;       // 2097152
  float* kb   = qb   + 2097152;       // 2097152
  float* vb   = kb   + 2097152;       // 2097152
  float* ao   = vb   + 2097152;       // 2097152
  float* mb   = ao   + 2097152;       // 524288
  float* outp = kvll;                 // reuse (kvll dead after conv k/v)
  float* id1  = qb;                   // reuse (qb dead after attn)
  float* stats = kb;                  // reuse (kb dead after attn), 128 floats

  qdwt_kernel<<<2048, 256, 0, stream>>>(query, qll, yh0, yh1);
  kvdwt_kernel<<<8192, 256, 0, stream>>>(kvm, kvll);

  dim3 gB(64, 16, 8), tB(16, 16);
  conv1x1_kernel<<<gB, tB, 0, stream>>>(qll,  Wq, bq, qb, 2);
  conv1x1_kernel<<<gB, tB, 0, stream>>>(kvll, Wk, bk, kb, 8);
  conv1x1_kernel<<<gB, tB, 0, stream>>>(kvll, Wv, bv, vb, 8);

  attn_kernel<<<256, 256, 0, stream>>>(qb, kb, vb, ao);

  conv1x1_kernel<<<gB, tB, 0, stream>>>(ao, Wp, bp, outp, 8);
  mean4_kernel<<<2048, 256, 0, stream>>>(outp, mb);

  idwt_kernel<<<2048, 256, 0, stream>>>(mb, yh1, id1, 32);
  idwt_kernel<<<8192, 256, 0, stream>>>(id1, yh0, out, 64);

  gn_stats_kernel<<<64, 256, 0, stream>>>(out, stats);
  gn_apply_kernel<<<8192, 256, 0, stream>>>(out, query, stats, gamma, beta);
}

// Round 2
// 443.533 us; speedup vs baseline: 1.7781x; 1.7781x over previous
//
#include <hip/hip_runtime.h>

// Problem constants: B=2, N=4, C=256, H=W=128, J=2, heads=8, hd=32, T=1024
// ws layout (floats):
//  qll  524288 | yh0 6291456 | yh1 1572864 | kvll 2097152 | qb 2097152
//  kb 2097152 | vb 2097152 | ao 2097152 | mb 524288   => 19,398,656 floats (74 MB)

typedef float f32x16 __attribute__((ext_vector_type(16)));
typedef short s16x8 __attribute__((ext_vector_type(8)));

static __device__ __forceinline__ unsigned f2bf_bits(float x) {
  unsigned u = __float_as_uint(x);
  return (u + 0x7fffu + ((u >> 16) & 1u)) >> 16;
}
static __device__ __forceinline__ unsigned pack2(float a, float b) {
  return f2bf_bits(a) | (f2bf_bits(b) << 16);
}

__global__ __launch_bounds__(256) void qdwt_kernel(const float* __restrict__ x,
    float* __restrict__ qll, float* __restrict__ yh0, float* __restrict__ yh1) {
  int idx = blockIdx.x * 256 + threadIdx.x;   // < 2*256*1024
  int bc = idx >> 10;
  int t  = idx & 1023;
  int i = t >> 5, j = t & 31;
  const float* xp = x + (size_t)bc * 16384;
  float r[4][4];
#pragma unroll
  for (int rr = 0; rr < 4; ++rr) {
    float4 v = *reinterpret_cast<const float4*>(xp + (4 * i + rr) * 128 + 4 * j);
    r[rr][0] = v.x; r[rr][1] = v.y; r[rr][2] = v.z; r[rr][3] = v.w;
  }
  float ll1[2][2];
  size_t b0 = (size_t)bc * 3 * 4096;
#pragma unroll
  for (int a = 0; a < 2; ++a)
#pragma unroll
    for (int b = 0; b < 2; ++b) {
      float x00 = r[2*a][2*b], x01 = r[2*a][2*b+1];
      float x10 = r[2*a+1][2*b], x11 = r[2*a+1][2*b+1];
      float ll = 0.5f * (x00 + x01 + x10 + x11);
      float lh = 0.5f * (x00 + x01 - x10 - x11);
      float hl = 0.5f * (x00 - x01 + x10 - x11);
      float hh = 0.5f * (x00 - x01 - x10 + x11);
      ll1[a][b] = ll;
      int pos = (2*i + a) * 64 + (2*j + b);
      yh0[b0 + pos]        = lh;
      yh0[b0 + 4096 + pos] = hl;
      yh0[b0 + 8192 + pos] = hh;
    }
  float x00 = ll1[0][0], x01 = ll1[0][1], x10 = ll1[1][0], x11 = ll1[1][1];
  float ll2 = 0.5f * (x00 + x01 + x10 + x11);
  float lh2 = 0.5f * (x00 + x01 - x10 - x11);
  float hl2 = 0.5f * (x00 - x01 + x10 - x11);
  float hh2 = 0.5f * (x00 - x01 - x10 + x11);
  qll[idx] = ll2;
  size_t b1 = (size_t)bc * 3 * 1024;
  yh1[b1 + t]        = lh2;
  yh1[b1 + 1024 + t] = hl2;
  yh1[b1 + 2048 + t] = hh2;
}

// kv: flat j = n*B + b reads key_value_multi[b, n]; output (j, C, 32, 32)
__global__ __launch_bounds__(256) void kvdwt_kernel(const float* __restrict__ kvm,
                                                    float* __restrict__ ll) {
  int idx = blockIdx.x * 256 + threadIdx.x;   // < 8*256*1024
  int bc = idx >> 10;      // j*256 + c
  int t  = idx & 1023;
  int i = t >> 5, j2 = t & 31;
  int jj = bc >> 8, c = bc & 255;
  int n = jj >> 1, b = jj & 1;
  const float* xp = kvm + ((size_t)(b * 4 + n) * 256 + c) * 16384;
  float s = 0.f;
#pragma unroll
  for (int rr = 0; rr < 4; ++rr) {
    float4 v = *reinterpret_cast<const float4*>(xp + (4 * i + rr) * 128 + 4 * j2);
    s += (v.x + v.y) + (v.z + v.w);
  }
  ll[idx] = 0.25f * s;
}

// Y[j][o][t] = sum_c W[o][c] * X[j % in_mod][c][t] + bias[o];  M=K=256, T=1024
__global__ __launch_bounds__(256) void conv1x1_kernel(const float* __restrict__ X,
    const float* __restrict__ Wm, const float* __restrict__ bias,
    float* __restrict__ Y, int in_mod) {
  int tx = threadIdx.x, ty = threadIdx.y;
  int t0 = blockIdx.x * 16, o0 = blockIdx.y * 16, j = blockIdx.z;
  const float* Xp = X + (size_t)(j % in_mod) * 262144;
  __shared__ float Wt[16][17];
  __shared__ float Xt[16][17];
  float acc = 0.f;
  for (int k0 = 0; k0 < 256; k0 += 16) {
    Wt[ty][tx] = Wm[(o0 + ty) * 256 + k0 + tx];
    Xt[ty][tx] = Xp[(size_t)(k0 + ty) * 1024 + t0 + tx];
    __syncthreads();
#pragma unroll
    for (int kk = 0; kk < 16; ++kk) acc += Wt[ty][kk] * Xt[kk][tx];
    __syncthreads();
  }
  Y[((size_t)j * 256 + o0 + ty) * 1024 + t0 + tx] = acc + bias[o0 + ty];
}

// ---------------------------------------------------------------------------
// MFMA flash attention.
// Buffers qb/kb/vb are [jh][d][t] with jh = j*8+h (stride 32768), d<32, t<1024.
// One wave per block; wave handles 32 queries (qbase..qbase+31) of one jh.
// S^T = mfma32x32x16(A=K[32k x 16d], B=Q^T[16d x 32q]) accumulated over d.
//   C layout: col = lane&31 = query, row = key = (reg&3)+8*(reg>>2)+4*(lane>>5)
// PV:  acc = mfma(A=P[32q x 16k], B=V[16k x 32d]) per 16-key chunk.
//   A layout: row = lane&31 = query (matches: lane owns its query's P row),
//             k-elems = (lane>>5)*8 + e.
// ---------------------------------------------------------------------------
__global__ __launch_bounds__(64) void attn_mfma_kernel(const float* __restrict__ qb,
    const float* __restrict__ kb, const float* __restrict__ vb,
    float* __restrict__ ao) {
  const int lane = threadIdx.x;
  const int hi   = lane >> 5;
  const int ln   = lane & 31;
  const int jh    = blockIdx.x >> 5;
  const int qbase = (blockIdx.x & 31) * 32;
  const size_t base = (size_t)jh * 32768;
  const float* qp = qb + base;
  const float* kp = kb + base;
  const float* vp = vb + base;

  // Q^T B-fragments: chunk c covers d = c*16 + hi*8 + e
  s16x8 Qf[2];
#pragma unroll
  for (int c = 0; c < 2; ++c) {
    union { s16x8 v; unsigned w[4]; } u;
#pragma unroll
    for (int e2 = 0; e2 < 4; ++e2) {
      int d = c * 16 + hi * 8 + e2 * 2;
      float a = qp[(size_t)d * 1024 + qbase + ln]       * 0.17677669529663687f;
      float b = qp[(size_t)(d + 1) * 1024 + qbase + ln] * 0.17677669529663687f;
      u.w[e2] = pack2(a, b);
    }
    Qf[c] = u.v;
  }

  f32x16 acc;
#pragma unroll
  for (int r = 0; r < 16; ++r) acc[r] = 0.f;
  float m = -1e30f, lsum = 0.f;

  for (int tile = 0; tile < 32; ++tile) {
    const int kb0 = tile * 32;
    // --- K A-fragments ---
    s16x8 Kf[2];
#pragma unroll
    for (int c = 0; c < 2; ++c) {
      union { s16x8 v; unsigned w[4]; } u;
#pragma unroll
      for (int e2 = 0; e2 < 4; ++e2) {
        int d = c * 16 + hi * 8 + e2 * 2;
        float a = kp[(size_t)d * 1024 + kb0 + ln];
        float b = kp[(size_t)(d + 1) * 1024 + kb0 + ln];
        u.w[e2] = pack2(a, b);
      }
      Kf[c] = u.v;
    }
    // --- S^T = K . Q^T  (32 keys x 32 queries) ---
    f32x16 S;
#pragma unroll
    for (int r = 0; r < 16; ++r) S[r] = 0.f;
    S = __builtin_amdgcn_mfma_f32_32x32x16_bf16(Kf[0], Qf[0], S, 0, 0, 0);
    S = __builtin_amdgcn_mfma_f32_32x32x16_bf16(Kf[1], Qf[1], S, 0, 0, 0);

    // --- online softmax (lane owns query ln; 16 of 32 keys, partner has rest)
    float tmax = S[0];
#pragma unroll
    for (int r = 1; r < 16; ++r) tmax = fmaxf(tmax, S[r]);
    tmax = fmaxf(tmax, __shfl_xor(tmax, 32));
    if (__any(tmax > m + 6.f)) {
      float nm = fmaxf(m, tmax);
      float f  = __expf(m - nm);
      m = nm;
      lsum *= f;
      int fi = __float_as_int(f);
#pragma unroll
      for (int r = 0; r < 16; ++r) {
        int row = (r & 3) + 8 * (r >> 2) + 4 * hi;
        float fr = __int_as_float(__builtin_amdgcn_ds_bpermute(row * 4, fi));
        acc[r] *= fr;
      }
    }
    float p[16];
#pragma unroll
    for (int r = 0; r < 16; ++r) {
      p[r] = __expf(S[r] - m);
      lsum += p[r];
    }
    // --- pack P rows to bf16 pairs (adjacent keys) ---
    unsigned P[8];
#pragma unroll
    for (int i = 0; i < 8; ++i) P[i] = pack2(p[2 * i], p[2 * i + 1]);

    // --- PV per 16-key chunk ---
#pragma unroll
    for (int c = 0; c < 2; ++c) {
      unsigned p0 = P[4 * c + 0], p1 = P[4 * c + 1];
      unsigned p2 = P[4 * c + 2], p3 = P[4 * c + 3];
      unsigned s0 = (unsigned)__shfl_xor((int)p0, 32);
      unsigned s1 = (unsigned)__shfl_xor((int)p1, 32);
      unsigned s2 = (unsigned)__shfl_xor((int)p2, 32);
      unsigned s3 = (unsigned)__shfl_xor((int)p3, 32);
      union { s16x8 v; unsigned w[4]; } pa;
      pa.w[0] = hi ? s2 : p0;
      pa.w[1] = hi ? s3 : p1;
      pa.w[2] = hi ? p2 : s0;
      pa.w[3] = hi ? p3 : s1;
      // V B-fragment: rows k = c*16 + hi*8 + e at col d = ln  (8 contiguous t)
      const float* vsrc = vp + (size_t)ln * 1024 + kb0 + c * 16 + hi * 8;
      float4 v0 = *reinterpret_cast<const float4*>(vsrc);
      float4 v1 = *reinterpret_cast<const float4*>(vsrc + 4);
      union { s16x8 v; unsigned w[4]; } vb2;
      vb2.w[0] = pack2(v0.x, v0.y);
      vb2.w[1] = pack2(v0.z, v0.w);
      vb2.w[2] = pack2(v1.x, v1.y);
      vb2.w[3] = pack2(v1.z, v1.w);
      acc = __builtin_amdgcn_mfma_f32_32x32x16_bf16(pa.v, vb2.v, acc, 0, 0, 0);
    }
  }

  float ltot = lsum + __shfl_xor(lsum, 32);
  float inv  = 1.f / ltot;      // for query (qbase + ln)

  // epilogue: transpose via LDS, scale by 1/l, coalesced store to ao[d][t]
  __shared__ float tileT[32 * 33];
#pragma unroll
  for (int r = 0; r < 16; ++r) {
    int row = (r & 3) + 8 * (r >> 2) + 4 * hi;   // query row
    tileT[row * 33 + ln] = acc[r];               // tileT[q][d]
  }
  __syncthreads();
#pragma unroll
  for (int pass = 0; pass < 16; ++pass) {
    int d = pass * 2 + hi;
    float v = tileT[ln * 33 + d] * inv;          // q = ln
    ao[base + (size_t)d * 1024 + qbase + ln] = v;
  }
}

// m[b'][c][t] = 0.25 * sum_{n'=0..3} outp[b'*4+n'][c][t]
__global__ __launch_bounds__(256) void mean4_kernel(const float* __restrict__ outp,
                                                    float* __restrict__ mb) {
  int idx = blockIdx.x * 256 + threadIdx.x;   // < 524288
  int bp = idx >> 18;
  int rem = idx & 262143;
  float s = 0.f;
#pragma unroll
  for (int n = 0; n < 4; ++n) s += outp[((size_t)(bp * 4 + n)) * 262144 + rem];
  mb[idx] = s * 0.25f;
}

// one inverse DWT level: ll (bc,hw,hw) + bands (bc,3,hw,hw) -> out (bc,2hw,2hw)
__global__ __launch_bounds__(256) void idwt_kernel(const float* __restrict__ ll,
    const float* __restrict__ bands, float* __restrict__ outp, int hw) {
  int idx = blockIdx.x * 256 + threadIdx.x;   // < 512*hw*hw
  int hw2 = hw * hw;
  int bc = idx / hw2;
  int t  = idx - bc * hw2;
  int i = t / hw, j = t - i * hw;
  float vll = ll[idx];
  size_t bb = (size_t)bc * 3 * hw2 + t;
  float lh = bands[bb], hl = bands[bb + hw2], hh = bands[bb + 2 * hw2];
  float a  = vll + lh, b2 = vll - lh;
  float c2 = hl + hh,  d2 = hl - hh;
  int W2 = 2 * hw;
  float2 row0 = make_float2(0.5f * (a + c2), 0.5f * (a - c2));
  float2 row1 = make_float2(0.5f * (b2 + d2), 0.5f * (b2 - d2));
  float* op = outp + (size_t)bc * W2 * W2;
  *reinterpret_cast<float2*>(op + (size_t)(2 * i) * W2 + 2 * j)     = row0;
  *reinterpret_cast<float2*>(op + (size_t)(2 * i + 1) * W2 + 2 * j) = row1;
}

// group stats: 64 groups (b*32+g), each 8 ch x 128 x 128 = 131072 contiguous floats
__global__ __launch_bounds__(256) void gn_stats_kernel(const float* __restrict__ pre,
                                                       float* __restrict__ stats) {
  int g = blockIdx.x;
  int tid = threadIdx.x;
  const float4* p = reinterpret_cast<const float4*>(pre + (size_t)g * 131072);
  float s = 0.f, s2 = 0.f;
  for (int e = tid; e < 32768; e += 256) {
    float4 v = p[e];
    s  += (v.x + v.y) + (v.z + v.w);
    s2 += (v.x * v.x + v.y * v.y) + (v.z * v.z + v.w * v.w);
  }
  __shared__ float ls[256], ls2[256];
  ls[tid] = s; ls2[tid] = s2;
  __syncthreads();
  for (int off = 128; off > 0; off >>= 1) {
    if (tid < off) { ls[tid] += ls[tid + off]; ls2[tid] += ls2[tid + off]; }
    __syncthreads();
  }
  if (tid == 0) {
    float mean = ls[0] * (1.f / 131072.f);
    float var  = ls2[0] * (1.f / 131072.f) - mean * mean;
    stats[g * 2]     = mean;
    stats[g * 2 + 1] = rsqrtf(var + 1e-5f);
  }
}

__global__ __launch_bounds__(256) void gn_apply_kernel(float* __restrict__ outp,
    const float* __restrict__ query, const float* __restrict__ stats,
    const float* __restrict__ gamma, const float* __restrict__ beta) {
  int idx = blockIdx.x * 256 + threadIdx.x;   // < 2097152 float4 units
  size_t e = (size_t)idx * 4;
  int c = (int)((e >> 14) & 255);
  int b = (int)(e >> 22);
  int g = b * 32 + (c >> 3);
  float mean = stats[g * 2], rstd = stats[g * 2 + 1];
  float ga = gamma[c], be = beta[c];
  float4 v = *reinterpret_cast<const float4*>(outp + e);
  float4 q = *reinterpret_cast<const float4*>(query + e);
  v.x = (v.x - mean) * rstd * ga + be + q.x;
  v.y = (v.y - mean) * rstd * ga + be + q.y;
  v.z = (v.z - mean) * rstd * ga + be + q.z;
  v.w = (v.w - mean) * rstd * ga + be + q.w;
  *reinterpret_cast<float4*>(outp + e) = v;
}

extern "C" void kernel_launch(void* const* d_in, const int* in_sizes, int n_in,
                              void* d_out, int out_size, void* d_ws, size_t ws_size,
                              hipStream_t stream) {
  const float* query = (const float*)d_in[0];
  const float* kvm   = (const float*)d_in[1];
  // d_in[2] = value_multi: unused by the reference
  const float* Wq = (const float*)d_in[3];
  const float* bq = (const float*)d_in[4];
  const float* Wk = (const float*)d_in[5];
  const float* bk = (const float*)d_in[6];
  const float* Wv = (const float*)d_in[7];
  const float* bv = (const float*)d_in[8];
  const float* Wp = (const float*)d_in[9];
  const float* bp = (const float*)d_in[10];
  const float* gamma = (const float*)d_in[11];
  const float* beta  = (const float*)d_in[12];
  float* out = (float*)d_out;
  float* ws  = (float*)d_ws;

  if (ws_size < (size_t)19398656 * 4) return;  // insufficient scratch

  float* qll  = ws;                   // 524288
  float* yh0  = qll  + 524288;        // 6291456
  float* yh1  = yh0  + 6291456;       // 1572864
  float* kvll = yh1  + 1572864;       // 2097152
  float* qb   = kvll + 2097152;       // 2097152
  float* kb   = qb   + 2097152;       // 2097152
  float* vb   = kb   + 2097152;       // 2097152
  float* ao   = vb   + 2097152;       // 2097152
  float* mb   = ao   + 2097152;       // 524288
  float* outp = kvll;                 // reuse (kvll dead after conv k/v)
  float* id1  = qb;                   // reuse (qb dead after attn)
  float* stats = kb;                  // reuse (kb dead after attn), 128 floats

  qdwt_kernel<<<2048, 256, 0, stream>>>(query, qll, yh0, yh1);
  kvdwt_kernel<<<8192, 256, 0, stream>>>(kvm, kvll);

  dim3 gB(64, 16, 8), tB(16, 16);
  conv1x1_kernel<<<gB, tB, 0, stream>>>(qll,  Wq, bq, qb, 2);
  conv1x1_kernel<<<gB, tB, 0, stream>>>(kvll, Wk, bk, kb, 8);
  conv1x1_kernel<<<gB, tB, 0, stream>>>(kvll, Wv, bv, vb, 8);

  attn_mfma_kernel<<<2048, 64, 0, stream>>>(qb, kb, vb, ao);

  conv1x1_kernel<<<gB, tB, 0, stream>>>(ao, Wp, bp, outp, 8);
  mean4_kernel<<<2048, 256, 0, stream>>>(outp, mb);

  idwt_kernel<<<2048, 256, 0, stream>>>(mb, yh1, id1, 32);
  idwt_kernel<<<8192, 256, 0, stream>>>(id1, yh0, out, 64);

  gn_stats_kernel<<<64, 256, 0, stream>>>(out, stats);
  gn_apply_kernel<<<8192, 256, 0, stream>>>(out, query, stats, gamma, beta);
}

// Round 3
// 223.548 us; speedup vs baseline: 3.5278x; 1.9841x over previous
//
#include <hip/hip_runtime.h>

// Problem constants: B=2, N=4, C=256, H=W=128, J=2, heads=8, hd=32, T=1024
// ws layout (floats):
//  qll  524288 | yh0 6291456 | yh1 1572864 | kvll 2097152 | qb 2097152
//  kb 2097152 | vb 2097152 | ao 2097152 | mb 524288   => 19,398,656 floats (74 MB)

typedef float f32x16 __attribute__((ext_vector_type(16)));
typedef short s16x8 __attribute__((ext_vector_type(8)));

static __device__ __forceinline__ unsigned f2bf_bits(float x) {
  unsigned u = __float_as_uint(x);
  return (u + 0x7fffu + ((u >> 16) & 1u)) >> 16;
}
static __device__ __forceinline__ unsigned pack2(float a, float b) {
  return f2bf_bits(a) | (f2bf_bits(b) << 16);
}
// XOR-swizzle for 128B-row LDS tiles: slot bits [6:4] ^= row bits [9:7]
static __device__ __forceinline__ int swz(int byte) {
  return byte ^ (((byte >> 7) & 7) << 4);
}

__global__ __launch_bounds__(256) void qdwt_kernel(const float* __restrict__ x,
    float* __restrict__ qll, float* __restrict__ yh0, float* __restrict__ yh1) {
  int idx = blockIdx.x * 256 + threadIdx.x;   // < 2*256*1024
  int bc = idx >> 10;
  int t  = idx & 1023;
  int i = t >> 5, j = t & 31;
  const float* xp = x + (size_t)bc * 16384;
  float r[4][4];
#pragma unroll
  for (int rr = 0; rr < 4; ++rr) {
    float4 v = *reinterpret_cast<const float4*>(xp + (4 * i + rr) * 128 + 4 * j);
    r[rr][0] = v.x; r[rr][1] = v.y; r[rr][2] = v.z; r[rr][3] = v.w;
  }
  float ll1[2][2];
  size_t b0 = (size_t)bc * 3 * 4096;
#pragma unroll
  for (int a = 0; a < 2; ++a)
#pragma unroll
    for (int b = 0; b < 2; ++b) {
      float x00 = r[2*a][2*b], x01 = r[2*a][2*b+1];
      float x10 = r[2*a+1][2*b], x11 = r[2*a+1][2*b+1];
      float ll = 0.5f * (x00 + x01 + x10 + x11);
      float lh = 0.5f * (x00 + x01 - x10 - x11);
      float hl = 0.5f * (x00 - x01 + x10 - x11);
      float hh = 0.5f * (x00 - x01 - x10 + x11);
      ll1[a][b] = ll;
      int pos = (2*i + a) * 64 + (2*j + b);
      yh0[b0 + pos]        = lh;
      yh0[b0 + 4096 + pos] = hl;
      yh0[b0 + 8192 + pos] = hh;
    }
  float x00 = ll1[0][0], x01 = ll1[0][1], x10 = ll1[1][0], x11 = ll1[1][1];
  float ll2 = 0.5f * (x00 + x01 + x10 + x11);
  float lh2 = 0.5f * (x00 + x01 - x10 - x11);
  float hl2 = 0.5f * (x00 - x01 + x10 - x11);
  float hh2 = 0.5f * (x00 - x01 - x10 + x11);
  qll[idx] = ll2;
  size_t b1 = (size_t)bc * 3 * 1024;
  yh1[b1 + t]        = lh2;
  yh1[b1 + 1024 + t] = hl2;
  yh1[b1 + 2048 + t] = hh2;
}

// kv: flat j = n*B + b reads key_value_multi[b, n]; output (j, C, 32, 32)
__global__ __launch_bounds__(256) void kvdwt_kernel(const float* __restrict__ kvm,
                                                    float* __restrict__ ll) {
  int idx = blockIdx.x * 256 + threadIdx.x;   // < 8*256*1024
  int bc = idx >> 10;      // j*256 + c
  int t  = idx & 1023;
  int i = t >> 5, j2 = t & 31;
  int jj = bc >> 8, c = bc & 255;
  int n = jj >> 1, b = jj & 1;
  const float* xp = kvm + ((size_t)(b * 4 + n) * 256 + c) * 16384;
  float s = 0.f;
#pragma unroll
  for (int rr = 0; rr < 4; ++rr) {
    float4 v = *reinterpret_cast<const float4*>(xp + (4 * i + rr) * 128 + 4 * j2);
    s += (v.x + v.y) + (v.z + v.w);
  }
  ll[idx] = 0.25f * s;
}

// ---------------------------------------------------------------------------
// MFMA conv1x1: Y[j][o][t] = sum_c W[o][c] * X[j%mod][c][t] + bias[o]
// Block: 4 waves, tile 64(o) x 128(t), BK=64. Grid (t/128, o/64, j).
// LDS: A-tile [o][k] 64x64 bf16 (8KB), B-tile [t][k] 128x64 bf16 (16KB),
// both 128B rows with period-8 XOR swizzle -> conflict-free b128 r/w.
// ---------------------------------------------------------------------------
__global__ __launch_bounds__(256) void conv1x1_mfma_kernel(const float* __restrict__ X,
    const float* __restrict__ Wm, const float* __restrict__ bias,
    float* __restrict__ Y, int in_mod) {
  const int tid = threadIdx.x;
  const int lane = tid & 63;
  const int w = tid >> 6;
  const int hi = lane >> 5;
  const int ln = lane & 31;
  const int o_off = (w >> 1) * 32;   // wave o-range within block tile
  const int t_off = (w & 1) * 64;    // wave t-range within block tile
  const int t0 = blockIdx.x * 128;
  const int o0 = blockIdx.y * 64;
  const int jj = blockIdx.z;
  const float* Xp = X + (size_t)(jj % in_mod) * 262144;

  __shared__ __align__(16) char lds[24576];
  char* ldsA = lds;           // 8KB: [o][k]
  char* ldsB = lds + 8192;    // 16KB: [t][k]

  f32x16 acc0, acc1;
#pragma unroll
  for (int r = 0; r < 16; ++r) { acc0[r] = 0.f; acc1[r] = 0.f; }

  // staging assignments
  const int oA = tid >> 2;           // 0..63
  const int kqA = (tid & 3) * 16;    // 0,16,32,48
  const int tB = tid & 127;          // 0..127
  const int kgB = (tid >> 7) * 4;    // 0 or 4

  for (int kk = 0; kk < 4; ++kk) {
    const int k0 = kk * 64;
    // --- stage A: W[o0+oA][k0+kqA .. +15] ---
    {
      const float* wp = Wm + (size_t)(o0 + oA) * 256 + k0 + kqA;
      float4 w0 = *reinterpret_cast<const float4*>(wp);
      float4 w1 = *reinterpret_cast<const float4*>(wp + 4);
      float4 w2 = *reinterpret_cast<const float4*>(wp + 8);
      float4 w3 = *reinterpret_cast<const float4*>(wp + 12);
      union { s16x8 v; unsigned u[4]; } a0, a1;
      a0.u[0] = pack2(w0.x, w0.y); a0.u[1] = pack2(w0.z, w0.w);
      a0.u[2] = pack2(w1.x, w1.y); a0.u[3] = pack2(w1.z, w1.w);
      a1.u[0] = pack2(w2.x, w2.y); a1.u[1] = pack2(w2.z, w2.w);
      a1.u[2] = pack2(w3.x, w3.y); a1.u[3] = pack2(w3.z, w3.w);
      int byte0 = oA * 128 + kqA * 2;
      *reinterpret_cast<s16x8*>(ldsA + swz(byte0))      = a0.v;
      *reinterpret_cast<s16x8*>(ldsA + swz(byte0 + 16)) = a1.v;
    }
    // --- stage B: X[k0+kg*8+e][t0+tB] for kg = kgB..kgB+3 ---
#pragma unroll
    for (int rep = 0; rep < 4; ++rep) {
      int kg = kgB + rep;
      const float* xp = Xp + (size_t)(k0 + kg * 8) * 1024 + t0 + tB;
      float v0 = xp[0];
      float v1 = xp[1024];
      float v2 = xp[2048];
      float v3 = xp[3072];
      float v4 = xp[4096];
      float v5 = xp[5120];
      float v6 = xp[6144];
      float v7 = xp[7168];
      union { s16x8 v; unsigned u[4]; } b;
      b.u[0] = pack2(v0, v1); b.u[1] = pack2(v2, v3);
      b.u[2] = pack2(v4, v5); b.u[3] = pack2(v6, v7);
      int byte = tB * 128 + kg * 16;
      *reinterpret_cast<s16x8*>(ldsB + swz(byte)) = b.v;
    }
    __syncthreads();
    // --- compute: 4 k-subs x (1 A-frag, 2 B-frags, 2 MFMA) ---
#pragma unroll
    for (int ks = 0; ks < 64; ks += 16) {
      int byteA = (o_off + ln) * 128 + ks * 2 + hi * 16;
      s16x8 af = *reinterpret_cast<const s16x8*>(ldsA + swz(byteA));
      int rowB0 = t_off + ln;
      int byteB0 = rowB0 * 128 + ks * 2 + hi * 16;
      s16x8 bf0 = *reinterpret_cast<const s16x8*>(ldsB + swz(byteB0));
      int byteB1 = (rowB0 + 32) * 128 + ks * 2 + hi * 16;
      s16x8 bf1 = *reinterpret_cast<const s16x8*>(ldsB + swz(byteB1));
      acc0 = __builtin_amdgcn_mfma_f32_32x32x16_bf16(af, bf0, acc0, 0, 0, 0);
      acc1 = __builtin_amdgcn_mfma_f32_32x32x16_bf16(af, bf1, acc1, 0, 0, 0);
    }
    __syncthreads();
  }

  // epilogue: C col = ln (t), row = (r&3)+8*(r>>2)+4*hi (o)
  size_t ybase = ((size_t)jj * 256 + o0) * 1024 + t0;
#pragma unroll
  for (int r = 0; r < 16; ++r) {
    int o = o_off + (r & 3) + 8 * (r >> 2) + 4 * hi;
    float bi = bias[o0 + o];
    Y[ybase + (size_t)o * 1024 + t_off + ln]      = acc0[r] + bi;
    Y[ybase + (size_t)o * 1024 + t_off + 32 + ln] = acc1[r] + bi;
  }
}

// ---------------------------------------------------------------------------
// MFMA flash attention (unchanged from round 1).
// ---------------------------------------------------------------------------
__global__ __launch_bounds__(64) void attn_mfma_kernel(const float* __restrict__ qb,
    const float* __restrict__ kb, const float* __restrict__ vb,
    float* __restrict__ ao) {
  const int lane = threadIdx.x;
  const int hi   = lane >> 5;
  const int ln   = lane & 31;
  const int jh    = blockIdx.x >> 5;
  const int qbase = (blockIdx.x & 31) * 32;
  const size_t base = (size_t)jh * 32768;
  const float* qp = qb + base;
  const float* kp = kb + base;
  const float* vp = vb + base;

  s16x8 Qf[2];
#pragma unroll
  for (int c = 0; c < 2; ++c) {
    union { s16x8 v; unsigned w[4]; } u;
#pragma unroll
    for (int e2 = 0; e2 < 4; ++e2) {
      int d = c * 16 + hi * 8 + e2 * 2;
      float a = qp[(size_t)d * 1024 + qbase + ln]       * 0.17677669529663687f;
      float b = qp[(size_t)(d + 1) * 1024 + qbase + ln] * 0.17677669529663687f;
      u.w[e2] = pack2(a, b);
    }
    Qf[c] = u.v;
  }

  f32x16 acc;
#pragma unroll
  for (int r = 0; r < 16; ++r) acc[r] = 0.f;
  float m = -1e30f, lsum = 0.f;

  for (int tile = 0; tile < 32; ++tile) {
    const int kb0 = tile * 32;
    s16x8 Kf[2];
#pragma unroll
    for (int c = 0; c < 2; ++c) {
      union { s16x8 v; unsigned w[4]; } u;
#pragma unroll
      for (int e2 = 0; e2 < 4; ++e2) {
        int d = c * 16 + hi * 8 + e2 * 2;
        float a = kp[(size_t)d * 1024 + kb0 + ln];
        float b = kp[(size_t)(d + 1) * 1024 + kb0 + ln];
        u.w[e2] = pack2(a, b);
      }
      Kf[c] = u.v;
    }
    f32x16 S;
#pragma unroll
    for (int r = 0; r < 16; ++r) S[r] = 0.f;
    S = __builtin_amdgcn_mfma_f32_32x32x16_bf16(Kf[0], Qf[0], S, 0, 0, 0);
    S = __builtin_amdgcn_mfma_f32_32x32x16_bf16(Kf[1], Qf[1], S, 0, 0, 0);

    float tmax = S[0];
#pragma unroll
    for (int r = 1; r < 16; ++r) tmax = fmaxf(tmax, S[r]);
    tmax = fmaxf(tmax, __shfl_xor(tmax, 32));
    if (__any(tmax > m + 6.f)) {
      float nm = fmaxf(m, tmax);
      float f  = __expf(m - nm);
      m = nm;
      lsum *= f;
      int fi = __float_as_int(f);
#pragma unroll
      for (int r = 0; r < 16; ++r) {
        int row = (r & 3) + 8 * (r >> 2) + 4 * hi;
        float fr = __int_as_float(__builtin_amdgcn_ds_bpermute(row * 4, fi));
        acc[r] *= fr;
      }
    }
    float p[16];
#pragma unroll
    for (int r = 0; r < 16; ++r) {
      p[r] = __expf(S[r] - m);
      lsum += p[r];
    }
    unsigned P[8];
#pragma unroll
    for (int i = 0; i < 8; ++i) P[i] = pack2(p[2 * i], p[2 * i + 1]);

#pragma unroll
    for (int c = 0; c < 2; ++c) {
      unsigned p0 = P[4 * c + 0], p1 = P[4 * c + 1];
      unsigned p2 = P[4 * c + 2], p3 = P[4 * c + 3];
      unsigned s0 = (unsigned)__shfl_xor((int)p0, 32);
      unsigned s1 = (unsigned)__shfl_xor((int)p1, 32);
      unsigned s2 = (unsigned)__shfl_xor((int)p2, 32);
      unsigned s3 = (unsigned)__shfl_xor((int)p3, 32);
      union { s16x8 v; unsigned w[4]; } pa;
      pa.w[0] = hi ? s2 : p0;
      pa.w[1] = hi ? s3 : p1;
      pa.w[2] = hi ? p2 : s0;
      pa.w[3] = hi ? p3 : s1;
      const float* vsrc = vp + (size_t)ln * 1024 + kb0 + c * 16 + hi * 8;
      float4 v0 = *reinterpret_cast<const float4*>(vsrc);
      float4 v1 = *reinterpret_cast<const float4*>(vsrc + 4);
      union { s16x8 v; unsigned w[4]; } vb2;
      vb2.w[0] = pack2(v0.x, v0.y);
      vb2.w[1] = pack2(v0.z, v0.w);
      vb2.w[2] = pack2(v1.x, v1.y);
      vb2.w[3] = pack2(v1.z, v1.w);
      acc = __builtin_amdgcn_mfma_f32_32x32x16_bf16(pa.v, vb2.v, acc, 0, 0, 0);
    }
  }

  float ltot = lsum + __shfl_xor(lsum, 32);
  float inv  = 1.f / ltot;

  __shared__ float tileT[32 * 33];
#pragma unroll
  for (int r = 0; r < 16; ++r) {
    int row = (r & 3) + 8 * (r >> 2) + 4 * hi;
    tileT[row * 33 + ln] = acc[r];
  }
  __syncthreads();
#pragma unroll
  for (int pass = 0; pass < 16; ++pass) {
    int d = pass * 2 + hi;
    float v = tileT[ln * 33 + d] * inv;
    ao[base + (size_t)d * 1024 + qbase + ln] = v;
  }
}

// m[b'][c][t] = 0.25 * sum_{n'=0..3} outp[b'*4+n'][c][t]
__global__ __launch_bounds__(256) void mean4_kernel(const float* __restrict__ outp,
                                                    float* __restrict__ mb) {
  int idx = blockIdx.x * 256 + threadIdx.x;   // < 524288
  int bp = idx >> 18;
  int rem = idx & 262143;
  float s = 0.f;
#pragma unroll
  for (int n = 0; n < 4; ++n) s += outp[((size_t)(bp * 4 + n)) * 262144 + rem];
  mb[idx] = s * 0.25f;
}

// one inverse DWT level: ll (bc,hw,hw) + bands (bc,3,hw,hw) -> out (bc,2hw,2hw)
__global__ __launch_bounds__(256) void idwt_kernel(const float* __restrict__ ll,
    const float* __restrict__ bands, float* __restrict__ outp, int hw) {
  int idx = blockIdx.x * 256 + threadIdx.x;   // < 512*hw*hw
  int hw2 = hw * hw;
  int bc = idx / hw2;
  int t  = idx - bc * hw2;
  int i = t / hw, j = t - i * hw;
  float vll = ll[idx];
  size_t bb = (size_t)bc * 3 * hw2 + t;
  float lh = bands[bb], hl = bands[bb + hw2], hh = bands[bb + 2 * hw2];
  float a  = vll + lh, b2 = vll - lh;
  float c2 = hl + hh,  d2 = hl - hh;
  int W2 = 2 * hw;
  float2 row0 = make_float2(0.5f * (a + c2), 0.5f * (a - c2));
  float2 row1 = make_float2(0.5f * (b2 + d2), 0.5f * (b2 - d2));
  float* op = outp + (size_t)bc * W2 * W2;
  *reinterpret_cast<float2*>(op + (size_t)(2 * i) * W2 + 2 * j)     = row0;
  *reinterpret_cast<float2*>(op + (size_t)(2 * i + 1) * W2 + 2 * j) = row1;
}

// group stats: 64 groups (b*32+g), each 8 ch x 128 x 128 = 131072 contiguous floats
__global__ __launch_bounds__(256) void gn_stats_kernel(const float* __restrict__ pre,
                                                       float* __restrict__ stats) {
  int g = blockIdx.x;
  int tid = threadIdx.x;
  const float4* p = reinterpret_cast<const float4*>(pre + (size_t)g * 131072);
  float s = 0.f, s2 = 0.f;
  for (int e = tid; e < 32768; e += 256) {
    float4 v = p[e];
    s  += (v.x + v.y) + (v.z + v.w);
    s2 += (v.x * v.x + v.y * v.y) + (v.z * v.z + v.w * v.w);
  }
  __shared__ float ls[256], ls2[256];
  ls[tid] = s; ls2[tid] = s2;
  __syncthreads();
  for (int off = 128; off > 0; off >>= 1) {
    if (tid < off) { ls[tid] += ls[tid + off]; ls2[tid] += ls2[tid + off]; }
    __syncthreads();
  }
  if (tid == 0) {
    float mean = ls[0] * (1.f / 131072.f);
    float var  = ls2[0] * (1.f / 131072.f) - mean * mean;
    stats[g * 2]     = mean;
    stats[g * 2 + 1] = rsqrtf(var + 1e-5f);
  }
}

__global__ __launch_bounds__(256) void gn_apply_kernel(float* __restrict__ outp,
    const float* __restrict__ query, const float* __restrict__ stats,
    const float* __restrict__ gamma, const float* __restrict__ beta) {
  int idx = blockIdx.x * 256 + threadIdx.x;   // < 2097152 float4 units
  size_t e = (size_t)idx * 4;
  int c = (int)((e >> 14) & 255);
  int b = (int)(e >> 22);
  int g = b * 32 + (c >> 3);
  float mean = stats[g * 2], rstd = stats[g * 2 + 1];
  float ga = gamma[c], be = beta[c];
  float4 v = *reinterpret_cast<const float4*>(outp + e);
  float4 q = *reinterpret_cast<const float4*>(query + e);
  v.x = (v.x - mean) * rstd * ga + be + q.x;
  v.y = (v.y - mean) * rstd * ga + be + q.y;
  v.z = (v.z - mean) * rstd * ga + be + q.z;
  v.w = (v.w - mean) * rstd * ga + be + q.w;
  *reinterpret_cast<float4*>(outp + e) = v;
}

extern "C" void kernel_launch(void* const* d_in, const int* in_sizes, int n_in,
                              void* d_out, int out_size, void* d_ws, size_t ws_size,
                              hipStream_t stream) {
  const float* query = (const float*)d_in[0];
  const float* kvm   = (const float*)d_in[1];
  // d_in[2] = value_multi: unused by the reference
  const float* Wq = (const float*)d_in[3];
  const float* bq = (const float*)d_in[4];
  const float* Wk = (const float*)d_in[5];
  const float* bk = (const float*)d_in[6];
  const float* Wv = (const float*)d_in[7];
  const float* bv = (const float*)d_in[8];
  const float* Wp = (const float*)d_in[9];
  const float* bp = (const float*)d_in[10];
  const float* gamma = (const float*)d_in[11];
  const float* beta  = (const float*)d_in[12];
  float* out = (float*)d_out;
  float* ws  = (float*)d_ws;

  if (ws_size < (size_t)19398656 * 4) return;  // insufficient scratch

  float* qll  = ws;                   // 524288
  float* yh0  = qll  + 524288;        // 6291456
  float* yh1  = yh0  + 6291456;       // 1572864
  float* kvll = yh1  + 1572864;       // 2097152
  float* qb   = kvll + 2097152;       // 2097152
  float* kb   = qb   + 2097152;       // 2097152
  float* vb   = kb   + 2097152;       // 2097152
  float* ao   = vb   + 2097152;       // 2097152
  float* mb   = ao   + 2097152;       // 524288
  float* outp = kvll;                 // reuse (kvll dead after conv k/v)
  float* id1  = qb;                   // reuse (qb dead after attn)
  float* stats = kb;                  // reuse (kb dead after attn), 128 floats

  qdwt_kernel<<<2048, 256, 0, stream>>>(query, qll, yh0, yh1);
  kvdwt_kernel<<<8192, 256, 0, stream>>>(kvm, kvll);

  dim3 gC(8, 4, 8);
  conv1x1_mfma_kernel<<<gC, 256, 0, stream>>>(qll,  Wq, bq, qb, 2);
  conv1x1_mfma_kernel<<<gC, 256, 0, stream>>>(kvll, Wk, bk, kb, 8);
  conv1x1_mfma_kernel<<<gC, 256, 0, stream>>>(kvll, Wv, bv, vb, 8);

  attn_mfma_kernel<<<2048, 64, 0, stream>>>(qb, kb, vb, ao);

  conv1x1_mfma_kernel<<<gC, 256, 0, stream>>>(ao, Wp, bp, outp, 8);
  mean4_kernel<<<2048, 256, 0, stream>>>(outp, mb);

  idwt_kernel<<<2048, 256, 0, stream>>>(mb, yh1, id1, 32);
  idwt_kernel<<<8192, 256, 0, stream>>>(id1, yh0, out, 64);

  gn_stats_kernel<<<64, 256, 0, stream>>>(out, stats);
  gn_apply_kernel<<<8192, 256, 0, stream>>>(out, query, stats, gamma, beta);
}

// Round 4
// 169.224 us; speedup vs baseline: 4.6603x; 1.3210x over previous
//
#include <hip/hip_runtime.h>

// Problem constants: B=2, N=4, C=256, H=W=128, J=2, heads=8, hd=32, T=1024
// ws layout (floats), 19,398,656 total (74 MB):
//  qll 524288 | yh0 6291456 | yh1 1572864 | kvll 2097152 | qb 2097152
//  kb 2097152 | vb 2097152 | ao 2097152 | mb 524288
// reuse: am=kvll, id1=qb, stats=kb

typedef float f32x16 __attribute__((ext_vector_type(16)));
typedef short s16x8 __attribute__((ext_vector_type(8)));

static __device__ __forceinline__ unsigned f2bf_bits(float x) {
  unsigned u = __float_as_uint(x);
  return (u + 0x7fffu + ((u >> 16) & 1u)) >> 16;
}
static __device__ __forceinline__ unsigned pack2(float a, float b) {
  return f2bf_bits(a) | (f2bf_bits(b) << 16);
}
// XOR-swizzle for 128B-row LDS tiles: slot bits [6:4] ^= row bits [9:7]
static __device__ __forceinline__ int swz(int byte) {
  return byte ^ (((byte >> 7) & 7) << 4);
}

__global__ __launch_bounds__(256) void qdwt_kernel(const float* __restrict__ x,
    float* __restrict__ qll, float* __restrict__ yh0, float* __restrict__ yh1) {
  int idx = blockIdx.x * 256 + threadIdx.x;   // < 2*256*1024
  int bc = idx >> 10;
  int t  = idx & 1023;
  int i = t >> 5, j = t & 31;
  const float* xp = x + (size_t)bc * 16384;
  float r[4][4];
#pragma unroll
  for (int rr = 0; rr < 4; ++rr) {
    float4 v = *reinterpret_cast<const float4*>(xp + (4 * i + rr) * 128 + 4 * j);
    r[rr][0] = v.x; r[rr][1] = v.y; r[rr][2] = v.z; r[rr][3] = v.w;
  }
  float ll1[2][2];
  size_t b0 = (size_t)bc * 3 * 4096;
#pragma unroll
  for (int a = 0; a < 2; ++a)
#pragma unroll
    for (int b = 0; b < 2; ++b) {
      float x00 = r[2*a][2*b], x01 = r[2*a][2*b+1];
      float x10 = r[2*a+1][2*b], x11 = r[2*a+1][2*b+1];
      float ll = 0.5f * (x00 + x01 + x10 + x11);
      float lh = 0.5f * (x00 + x01 - x10 - x11);
      float hl = 0.5f * (x00 - x01 + x10 - x11);
      float hh = 0.5f * (x00 - x01 - x10 + x11);
      ll1[a][b] = ll;
      int pos = (2*i + a) * 64 + (2*j + b);
      yh0[b0 + pos]        = lh;
      yh0[b0 + 4096 + pos] = hl;
      yh0[b0 + 8192 + pos] = hh;
    }
  float x00 = ll1[0][0], x01 = ll1[0][1], x10 = ll1[1][0], x11 = ll1[1][1];
  float ll2 = 0.5f * (x00 + x01 + x10 + x11);
  float lh2 = 0.5f * (x00 + x01 - x10 - x11);
  float hl2 = 0.5f * (x00 - x01 + x10 - x11);
  float hh2 = 0.5f * (x00 - x01 - x10 + x11);
  qll[idx] = ll2;
  size_t b1 = (size_t)bc * 3 * 1024;
  yh1[b1 + t]        = lh2;
  yh1[b1 + 1024 + t] = hl2;
  yh1[b1 + 2048 + t] = hh2;
}

// kv: flat j = n*B + b reads key_value_multi[b, n]; output (j, C, 32, 32)
__global__ __launch_bounds__(256) void kvdwt_kernel(const float* __restrict__ kvm,
                                                    float* __restrict__ ll) {
  int idx = blockIdx.x * 256 + threadIdx.x;   // < 8*256*1024
  int bc = idx >> 10;      // j*256 + c
  int t  = idx & 1023;
  int i = t >> 5, j2 = t & 31;
  int jj = bc >> 8, c = bc & 255;
  int n = jj >> 1, b = jj & 1;
  const float* xp = kvm + ((size_t)(b * 4 + n) * 256 + c) * 16384;
  float s = 0.f;
#pragma unroll
  for (int rr = 0; rr < 4; ++rr) {
    float4 v = *reinterpret_cast<const float4*>(xp + (4 * i + rr) * 128 + 4 * j2);
    s += (v.x + v.y) + (v.z + v.w);
  }
  ll[idx] = 0.25f * s;
}

// --- conv helpers ------------------------------------------------------
static __device__ __forceinline__ void stage_w_tile(const float* __restrict__ Wm,
    char* ldsA, int o0, int k0, int oA, int kqA) {
  const float* wp = Wm + (size_t)(o0 + oA) * 256 + k0 + kqA;
  float4 w0 = *reinterpret_cast<const float4*>(wp);
  float4 w1 = *reinterpret_cast<const float4*>(wp + 4);
  float4 w2 = *reinterpret_cast<const float4*>(wp + 8);
  float4 w3 = *reinterpret_cast<const float4*>(wp + 12);
  union { s16x8 v; unsigned u[4]; } a0, a1;
  a0.u[0] = pack2(w0.x, w0.y); a0.u[1] = pack2(w0.z, w0.w);
  a0.u[2] = pack2(w1.x, w1.y); a0.u[3] = pack2(w1.z, w1.w);
  a1.u[0] = pack2(w2.x, w2.y); a1.u[1] = pack2(w2.z, w2.w);
  a1.u[2] = pack2(w3.x, w3.y); a1.u[3] = pack2(w3.z, w3.w);
  int byte0 = oA * 128 + kqA * 2;
  *reinterpret_cast<s16x8*>(ldsA + swz(byte0))      = a0.v;
  *reinterpret_cast<s16x8*>(ldsA + swz(byte0 + 16)) = a1.v;
}

static __device__ __forceinline__ void stage_x_tile(const float* __restrict__ Xp,
    char* ldsB, int k0, int t0, int tB, int kg0) {
#pragma unroll
  for (int rep = 0; rep < 2; ++rep) {
    int kg = kg0 + rep * 4;
    const float* xp = Xp + (size_t)(k0 + kg * 8) * 1024 + t0 + tB;
    float v0 = xp[0];
    float v1 = xp[1024];
    float v2 = xp[2048];
    float v3 = xp[3072];
    float v4 = xp[4096];
    float v5 = xp[5120];
    float v6 = xp[6144];
    float v7 = xp[7168];
    union { s16x8 v; unsigned u[4]; } b;
    b.u[0] = pack2(v0, v1); b.u[1] = pack2(v2, v3);
    b.u[2] = pack2(v4, v5); b.u[3] = pack2(v6, v7);
    *reinterpret_cast<s16x8*>(ldsB + swz(tB * 128 + kg * 16)) = b.v;
  }
}

// ---------------------------------------------------------------------------
// MFMA conv1x1 (single output): tile 64o x 64t, 4 waves (32x32 each), BK=64.
// ---------------------------------------------------------------------------
__global__ __launch_bounds__(256) void conv_s_kernel(const float* __restrict__ X,
    const float* __restrict__ Wm, const float* __restrict__ bias,
    float* __restrict__ Y, int in_mod) {
  const int tid = threadIdx.x;
  const int hi = (tid >> 5) & 1;
  const int ln = tid & 31;
  const int w = tid >> 6;
  const int o_off = (w >> 1) * 32;
  const int t_off = (w & 1) * 32;
  const int t0 = blockIdx.x * 64;
  const int o0 = blockIdx.y * 64;
  const int jj = blockIdx.z;
  const float* Xp = X + (size_t)(jj % in_mod) * 262144;

  __shared__ __align__(16) char lds[16384];
  char* ldsA = lds;
  char* ldsB = lds + 8192;

  f32x16 acc;
#pragma unroll
  for (int r = 0; r < 16; ++r) acc[r] = 0.f;

  const int oA = tid >> 2;
  const int kqA = (tid & 3) * 16;
  const int tB = tid & 63;
  const int kg0 = tid >> 6;

  for (int kk = 0; kk < 4; ++kk) {
    const int k0 = kk * 64;
    stage_w_tile(Wm, ldsA, o0, k0, oA, kqA);
    stage_x_tile(Xp, ldsB, k0, t0, tB, kg0);
    __syncthreads();
#pragma unroll
    for (int ks = 0; ks < 64; ks += 16) {
      s16x8 af = *reinterpret_cast<const s16x8*>(ldsA + swz((o_off + ln) * 128 + ks * 2 + hi * 16));
      s16x8 bf = *reinterpret_cast<const s16x8*>(ldsB + swz((t_off + ln) * 128 + ks * 2 + hi * 16));
      acc = __builtin_amdgcn_mfma_f32_32x32x16_bf16(af, bf, acc, 0, 0, 0);
    }
    __syncthreads();
  }

  size_t ybase = ((size_t)jj * 256 + o0) * 1024 + t0;
#pragma unroll
  for (int r = 0; r < 16; ++r) {
    int o = o_off + (r & 3) + 8 * (r >> 2) + 4 * hi;
    Y[ybase + (size_t)o * 1024 + t_off + ln] = acc[r] + bias[o0 + o];
  }
}

// ---------------------------------------------------------------------------
// MFMA conv1x1 (dual output, shared X staging): Yk = Wk X + bk, Yv = Wv X + bv
// ---------------------------------------------------------------------------
__global__ __launch_bounds__(256) void conv_d_kernel(const float* __restrict__ X,
    const float* __restrict__ Wk, const float* __restrict__ bk,
    const float* __restrict__ Wv, const float* __restrict__ bv,
    float* __restrict__ Yk, float* __restrict__ Yv) {
  const int tid = threadIdx.x;
  const int hi = (tid >> 5) & 1;
  const int ln = tid & 31;
  const int w = tid >> 6;
  const int o_off = (w >> 1) * 32;
  const int t_off = (w & 1) * 32;
  const int t0 = blockIdx.x * 64;
  const int o0 = blockIdx.y * 64;
  const int jj = blockIdx.z;
  const float* Xp = X + (size_t)jj * 262144;

  __shared__ __align__(16) char lds[24576];
  char* ldsAk = lds;
  char* ldsAv = lds + 8192;
  char* ldsB  = lds + 16384;

  f32x16 acck, accv;
#pragma unroll
  for (int r = 0; r < 16; ++r) { acck[r] = 0.f; accv[r] = 0.f; }

  const int oA = tid >> 2;
  const int kqA = (tid & 3) * 16;
  const int tB = tid & 63;
  const int kg0 = tid >> 6;

  for (int kk = 0; kk < 4; ++kk) {
    const int k0 = kk * 64;
    stage_w_tile(Wk, ldsAk, o0, k0, oA, kqA);
    stage_w_tile(Wv, ldsAv, o0, k0, oA, kqA);
    stage_x_tile(Xp, ldsB, k0, t0, tB, kg0);
    __syncthreads();
#pragma unroll
    for (int ks = 0; ks < 64; ks += 16) {
      s16x8 bf  = *reinterpret_cast<const s16x8*>(ldsB  + swz((t_off + ln) * 128 + ks * 2 + hi * 16));
      s16x8 afk = *reinterpret_cast<const s16x8*>(ldsAk + swz((o_off + ln) * 128 + ks * 2 + hi * 16));
      s16x8 afv = *reinterpret_cast<const s16x8*>(ldsAv + swz((o_off + ln) * 128 + ks * 2 + hi * 16));
      acck = __builtin_amdgcn_mfma_f32_32x32x16_bf16(afk, bf, acck, 0, 0, 0);
      accv = __builtin_amdgcn_mfma_f32_32x32x16_bf16(afv, bf, accv, 0, 0, 0);
    }
    __syncthreads();
  }

  size_t ybase = ((size_t)jj * 256 + o0) * 1024 + t0;
#pragma unroll
  for (int r = 0; r < 16; ++r) {
    int o = o_off + (r & 3) + 8 * (r >> 2) + 4 * hi;
    Yk[ybase + (size_t)o * 1024 + t_off + ln] = acck[r] + bk[o0 + o];
    Yv[ybase + (size_t)o * 1024 + t_off + ln] = accv[r] + bv[o0 + o];
  }
}

// ---------------------------------------------------------------------------
// MFMA flash attention, 4 waves/block sharing LDS-staged K/V tiles.
// qb holds only j=0,1 (16 jh); kb/vb full 64 jh, layout [jh][d][t].
// K tile LDS: KpL[key 0..31][d-pair 0..15 (+1 pad)] packed bf16 pairs over d.
// V tile LDS: VpL[d 0..31][key-pair 0..15 (+1 pad)] packed bf16 pairs over k.
// 17-stride rows -> conflict-free (17 coprime 32). Double-buffered,
// load-early / ds_write-late (T14).
// ---------------------------------------------------------------------------
__global__ __launch_bounds__(256) void attn_mfma_kernel(const float* __restrict__ qb,
    const float* __restrict__ kb, const float* __restrict__ vb,
    float* __restrict__ ao) {
  const int tid = threadIdx.x;
  const int w   = tid >> 6;
  const int hi  = (tid >> 5) & 1;
  const int ln  = tid & 31;
  const int jh  = blockIdx.x >> 3;
  const int qg  = blockIdx.x & 7;
  const int qbase = (qg * 4 + w) * 32;
  const size_t base = (size_t)jh * 32768;
  const int j = jh >> 3, h = jh & 7;
  const float* qp = qb + (size_t)((j & 1) * 8 + h) * 32768;
  const float* kp = kb + base;
  const float* vp = vb + base;

  __shared__ unsigned KpL[2][544];
  __shared__ unsigned VpL[2][544];
  __shared__ float tileT[4][1056];

  // staging indices
  const int sdp = tid >> 5;   // K d-pair base (0..7; +8 second pass)
  const int st  = tid & 31;   // K key index
  const int svd = tid >> 4;   // V d base (0..15; +16 second pass)
  const int svt = tid & 15;   // V key-pair index

  // Q^T B-fragments: chunk c covers d = c*16 + hi*8 + e
  s16x8 Qf[2];
#pragma unroll
  for (int c = 0; c < 2; ++c) {
    union { s16x8 v; unsigned u[4]; } u;
#pragma unroll
    for (int e2 = 0; e2 < 4; ++e2) {
      int d = c * 16 + hi * 8 + e2 * 2;
      float a = qp[(size_t)d * 1024 + qbase + ln]       * 0.17677669529663687f;
      float b = qp[(size_t)(d + 1) * 1024 + qbase + ln] * 0.17677669529663687f;
      u.u[e2] = pack2(a, b);
    }
    Qf[c] = u.v;
  }

  f32x16 acc;
#pragma unroll
  for (int r = 0; r < 16; ++r) acc[r] = 0.f;
  float m = -1e30f, lsum = 0.f;

  // prologue: stage tile 0 into buffer 0
  {
    float ka0 = kp[(size_t)(2 * sdp) * 1024 + st];
    float kb0v = kp[(size_t)(2 * sdp + 1) * 1024 + st];
    float ka1 = kp[(size_t)(2 * (sdp + 8)) * 1024 + st];
    float kb1v = kp[(size_t)(2 * (sdp + 8) + 1) * 1024 + st];
    float2 v0 = *reinterpret_cast<const float2*>(vp + (size_t)svd * 1024 + 2 * svt);
    float2 v1 = *reinterpret_cast<const float2*>(vp + (size_t)(svd + 16) * 1024 + 2 * svt);
    KpL[0][st * 17 + sdp]     = pack2(ka0, kb0v);
    KpL[0][st * 17 + sdp + 8] = pack2(ka1, kb1v);
    VpL[0][svd * 17 + svt]        = pack2(v0.x, v0.y);
    VpL[0][(svd + 16) * 17 + svt] = pack2(v1.x, v1.y);
  }
  __syncthreads();

  for (int tile = 0; tile < 32; ++tile) {
    const int cur = tile & 1;
    // issue next-tile global loads early (latency hides under compute)
    float nka0 = 0.f, nkb0 = 0.f, nka1 = 0.f, nkb1 = 0.f;
    float2 nv0 = make_float2(0.f, 0.f), nv1 = make_float2(0.f, 0.f);
    if (tile < 31) {
      const int kn = (tile + 1) * 32;
      nka0 = kp[(size_t)(2 * sdp) * 1024 + kn + st];
      nkb0 = kp[(size_t)(2 * sdp + 1) * 1024 + kn + st];
      nka1 = kp[(size_t)(2 * (sdp + 8)) * 1024 + kn + st];
      nkb1 = kp[(size_t)(2 * (sdp + 8) + 1) * 1024 + kn + st];
      nv0 = *reinterpret_cast<const float2*>(vp + (size_t)svd * 1024 + kn + 2 * svt);
      nv1 = *reinterpret_cast<const float2*>(vp + (size_t)(svd + 16) * 1024 + kn + 2 * svt);
    }

    // --- K A-fragments from LDS ---
    s16x8 Kf[2];
#pragma unroll
    for (int c = 0; c < 2; ++c) {
      union { s16x8 v; unsigned u[4]; } u;
#pragma unroll
      for (int e = 0; e < 4; ++e)
        u.u[e] = KpL[cur][ln * 17 + c * 8 + hi * 4 + e];
      Kf[c] = u.v;
    }
    // --- S^T = K . Q^T ---
    f32x16 S;
#pragma unroll
    for (int r = 0; r < 16; ++r) S[r] = 0.f;
    S = __builtin_amdgcn_mfma_f32_32x32x16_bf16(Kf[0], Qf[0], S, 0, 0, 0);
    S = __builtin_amdgcn_mfma_f32_32x32x16_bf16(Kf[1], Qf[1], S, 0, 0, 0);

    // --- online softmax (lane owns query ln) ---
    float tmax = S[0];
#pragma unroll
    for (int r = 1; r < 16; ++r) tmax = fmaxf(tmax, S[r]);
    tmax = fmaxf(tmax, __shfl_xor(tmax, 32));
    if (__any(tmax > m + 6.f)) {
      float nm = fmaxf(m, tmax);
      float f  = __expf(m - nm);
      m = nm;
      lsum *= f;
      int fi = __float_as_int(f);
#pragma unroll
      for (int r = 0; r < 16; ++r) {
        int row = (r & 3) + 8 * (r >> 2) + 4 * hi;
        float fr = __int_as_float(__builtin_amdgcn_ds_bpermute(row * 4, fi));
        acc[r] *= fr;
      }
    }
    float p[16];
#pragma unroll
    for (int r = 0; r < 16; ++r) {
      p[r] = __expf(S[r] - m);
      lsum += p[r];
    }
    unsigned P[8];
#pragma unroll
    for (int i = 0; i < 8; ++i) P[i] = pack2(p[2 * i], p[2 * i + 1]);

    // --- PV per 16-key chunk, V from LDS ---
#pragma unroll
    for (int c = 0; c < 2; ++c) {
      unsigned p0 = P[4 * c + 0], p1 = P[4 * c + 1];
      unsigned p2 = P[4 * c + 2], p3 = P[4 * c + 3];
      unsigned s0 = (unsigned)__shfl_xor((int)p0, 32);
      unsigned s1 = (unsigned)__shfl_xor((int)p1, 32);
      unsigned s2 = (unsigned)__shfl_xor((int)p2, 32);
      unsigned s3 = (unsigned)__shfl_xor((int)p3, 32);
      union { s16x8 v; unsigned u[4]; } pa;
      pa.u[0] = hi ? s2 : p0;
      pa.u[1] = hi ? s3 : p1;
      pa.u[2] = hi ? p2 : s0;
      pa.u[3] = hi ? p3 : s1;
      union { s16x8 v; unsigned u[4]; } vf;
#pragma unroll
      for (int e = 0; e < 4; ++e)
        vf.u[e] = VpL[cur][ln * 17 + c * 8 + hi * 4 + e];
      acc = __builtin_amdgcn_mfma_f32_32x32x16_bf16(pa.v, vf.v, acc, 0, 0, 0);
    }

    // --- write next tile's staged data (after compute) ---
    if (tile < 31) {
      const int nxt = cur ^ 1;
      KpL[nxt][st * 17 + sdp]     = pack2(nka0, nkb0);
      KpL[nxt][st * 17 + sdp + 8] = pack2(nka1, nkb1);
      VpL[nxt][svd * 17 + svt]        = pack2(nv0.x, nv0.y);
      VpL[nxt][(svd + 16) * 17 + svt] = pack2(nv1.x, nv1.y);
    }
    __syncthreads();
  }

  float ltot = lsum + __shfl_xor(lsum, 32);
  float inv  = 1.f / ltot;      // for query (qbase + ln)

  // epilogue: per-wave transpose via LDS, scale by 1/l, coalesced store
  float* tw = tileT[w];
#pragma unroll
  for (int r = 0; r < 16; ++r) {
    int row = (r & 3) + 8 * (r >> 2) + 4 * hi;   // query row
    tw[row * 33 + ln] = acc[r];                  // tw[q][d]
  }
  __syncthreads();
#pragma unroll
  for (int pass = 0; pass < 16; ++pass) {
    int d = pass * 2 + hi;
    float v = tw[ln * 33 + d] * inv;             // q = ln
    ao[base + (size_t)d * 1024 + qbase + ln] = v;
  }
}

// am[bp][c][t] = 0.25 * sum_{n=0..3} ao[(bp*4+n)][c][t]
__global__ __launch_bounds__(256) void mean4_kernel(const float* __restrict__ src,
                                                    float* __restrict__ dst) {
  int idx = blockIdx.x * 256 + threadIdx.x;   // < 524288
  int bp = idx >> 18;
  int rem = idx & 262143;
  float s = 0.f;
#pragma unroll
  for (int n = 0; n < 4; ++n) s += src[((size_t)(bp * 4 + n)) * 262144 + rem];
  dst[idx] = s * 0.25f;
}

// one inverse DWT level: ll (bc,hw,hw) + bands (bc,3,hw,hw) -> out (bc,2hw,2hw)
__global__ __launch_bounds__(256) void idwt_kernel(const float* __restrict__ ll,
    const float* __restrict__ bands, float* __restrict__ outp, int hw) {
  int idx = blockIdx.x * 256 + threadIdx.x;   // < 512*hw*hw
  int hw2 = hw * hw;
  int bc = idx / hw2;
  int t  = idx - bc * hw2;
  int i = t / hw, j = t - i * hw;
  float vll = ll[idx];
  size_t bb = (size_t)bc * 3 * hw2 + t;
  float lh = bands[bb], hl = bands[bb + hw2], hh = bands[bb + 2 * hw2];
  float a  = vll + lh, b2 = vll - lh;
  float c2 = hl + hh,  d2 = hl - hh;
  int W2 = 2 * hw;
  float2 row0 = make_float2(0.5f * (a + c2), 0.5f * (a - c2));
  float2 row1 = make_float2(0.5f * (b2 + d2), 0.5f * (b2 - d2));
  float* op = outp + (size_t)bc * W2 * W2;
  *reinterpret_cast<float2*>(op + (size_t)(2 * i) * W2 + 2 * j)     = row0;
  *reinterpret_cast<float2*>(op + (size_t)(2 * i + 1) * W2 + 2 * j) = row1;
}

// group stats: 64 groups (b*32+g), each 8 ch x 128 x 128 = 131072 contiguous floats
__global__ __launch_bounds__(256) void gn_stats_kernel(const float* __restrict__ pre,
                                                       float* __restrict__ stats) {
  int g = blockIdx.x;
  int tid = threadIdx.x;
  const float4* p = reinterpret_cast<const float4*>(pre + (size_t)g * 131072);
  float s = 0.f, s2 = 0.f;
  for (int e = tid; e < 32768; e += 256) {
    float4 v = p[e];
    s  += (v.x + v.y) + (v.z + v.w);
    s2 += (v.x * v.x + v.y * v.y) + (v.z * v.z + v.w * v.w);
  }
  __shared__ float ls[256], ls2[256];
  ls[tid] = s; ls2[tid] = s2;
  __syncthreads();
  for (int off = 128; off > 0; off >>= 1) {
    if (tid < off) { ls[tid] += ls[tid + off]; ls2[tid] += ls2[tid + off]; }
    __syncthreads();
  }
  if (tid == 0) {
    float mean = ls[0] * (1.f / 131072.f);
    float var  = ls2[0] * (1.f / 131072.f) - mean * mean;
    stats[g * 2]     = mean;
    stats[g * 2 + 1] = rsqrtf(var + 1e-5f);
  }
}

__global__ __launch_bounds__(256) void gn_apply_kernel(float* __restrict__ outp,
    const float* __restrict__ query, const float* __restrict__ stats,
    const float* __restrict__ gamma, const float* __restrict__ beta) {
  int idx = blockIdx.x * 256 + threadIdx.x;   // < 2097152 float4 units
  size_t e = (size_t)idx * 4;
  int c = (int)((e >> 14) & 255);
  int b = (int)(e >> 22);
  int g = b * 32 + (c >> 3);
  float mean = stats[g * 2], rstd = stats[g * 2 + 1];
  float ga = gamma[c], be = beta[c];
  float4 v = *reinterpret_cast<const float4*>(outp + e);
  float4 q = *reinterpret_cast<const float4*>(query + e);
  v.x = (v.x - mean) * rstd * ga + be + q.x;
  v.y = (v.y - mean) * rstd * ga + be + q.y;
  v.z = (v.z - mean) * rstd * ga + be + q.z;
  v.w = (v.w - mean) * rstd * ga + be + q.w;
  *reinterpret_cast<float4*>(outp + e) = v;
}

extern "C" void kernel_launch(void* const* d_in, const int* in_sizes, int n_in,
                              void* d_out, int out_size, void* d_ws, size_t ws_size,
                              hipStream_t stream) {
  const float* query = (const float*)d_in[0];
  const float* kvm   = (const float*)d_in[1];
  // d_in[2] = value_multi: unused by the reference
  const float* Wq = (const float*)d_in[3];
  const float* bq = (const float*)d_in[4];
  const float* Wk = (const float*)d_in[5];
  const float* bk = (const float*)d_in[6];
  const float* Wv = (const float*)d_in[7];
  const float* bv = (const float*)d_in[8];
  const float* Wp = (const float*)d_in[9];
  const float* bp = (const float*)d_in[10];
  const float* gamma = (const float*)d_in[11];
  const float* beta  = (const float*)d_in[12];
  float* out = (float*)d_out;
  float* ws  = (float*)d_ws;

  if (ws_size < (size_t)19398656 * 4) return;  // insufficient scratch

  float* qll  = ws;                   // 524288
  float* yh0  = qll  + 524288;        // 6291456
  float* yh1  = yh0  + 6291456;       // 1572864
  float* kvll = yh1  + 1572864;       // 2097152
  float* qb   = kvll + 2097152;       // 2097152 (only 524288 used: j=0,1)
  float* kb   = qb   + 2097152;       // 2097152
  float* vb   = kb   + 2097152;       // 2097152
  float* ao   = vb   + 2097152;       // 2097152
  float* mb   = ao   + 2097152;       // 524288
  float* am   = kvll;                 // reuse (kvll dead after conv kv)
  float* id1  = qb;                   // reuse (qb dead after attn)
  float* stats = kb;                  // reuse (kb dead after attn), 128 floats

  qdwt_kernel<<<2048, 256, 0, stream>>>(query, qll, yh0, yh1);
  kvdwt_kernel<<<8192, 256, 0, stream>>>(kvm, kvll);

  conv_s_kernel<<<dim3(16, 4, 2), 256, 0, stream>>>(qll, Wq, bq, qb, 2);
  conv_d_kernel<<<dim3(16, 4, 8), 256, 0, stream>>>(kvll, Wk, bk, Wv, bv, kb, vb);

  attn_mfma_kernel<<<512, 256, 0, stream>>>(qb, kb, vb, ao);

  mean4_kernel<<<2048, 256, 0, stream>>>(ao, am);
  conv_s_kernel<<<dim3(16, 4, 2), 256, 0, stream>>>(am, Wp, bp, mb, 2);

  idwt_kernel<<<2048, 256, 0, stream>>>(mb, yh1, id1, 32);
  idwt_kernel<<<8192, 256, 0, stream>>>(id1, yh0, out, 64);

  gn_stats_kernel<<<64, 256, 0, stream>>>(out, stats);
  gn_apply_kernel<<<8192, 256, 0, stream>>>(out, query, stats, gamma, beta);
}

// Round 5
// 120.015 us; speedup vs baseline: 6.5712x; 1.4100x over previous
//
#include <hip/hip_runtime.h>

// Problem constants: B=2, N=4, C=256, H=W=128, J=2, heads=8, hd=32, T=1024
// ws layout (floats), total 17,827,968 (71.3 MB):
//  qll 524288 | yh0 6291456 | yh1 1572864 | kvll 2097152 | qb 524288
//  kb 2097152 | vb 2097152 | ao 2097152 | mb 524288 | partial 2048 | stats 128
// GroupNorm stats are computed PRE-idwt via orthonormality of the Haar DWT:
//   sum(out) = 4*sum(mb);  sum(out^2) = sum(mb^2) + sum(yh1^2) + sum(yh0^2).

typedef float f32x16 __attribute__((ext_vector_type(16)));
typedef short s16x8 __attribute__((ext_vector_type(8)));

static __device__ __forceinline__ unsigned f2bf_bits(float x) {
  unsigned u = __float_as_uint(x);
  return (u + 0x7fffu + ((u >> 16) & 1u)) >> 16;
}
static __device__ __forceinline__ unsigned pack2(float a, float b) {
  return f2bf_bits(a) | (f2bf_bits(b) << 16);
}
// XOR-swizzle for 128B-row LDS tiles: slot bits [6:4] ^= row bits [9:7]
static __device__ __forceinline__ int swz(int byte) {
  return byte ^ (((byte >> 7) & 7) << 4);
}

// DWT J=2 of query + per-block band-energy partial sums (for GroupNorm).
__global__ __launch_bounds__(256) void qdwt_kernel(const float* __restrict__ x,
    float* __restrict__ qll, float* __restrict__ yh0, float* __restrict__ yh1,
    float* __restrict__ partial) {
  int idx = blockIdx.x * 256 + threadIdx.x;   // < 2*256*1024
  int bc = idx >> 10;
  int t  = idx & 1023;
  int i = t >> 5, j = t & 31;
  const float* xp = x + (size_t)bc * 16384;
  float r[4][4];
#pragma unroll
  for (int rr = 0; rr < 4; ++rr) {
    float4 v = *reinterpret_cast<const float4*>(xp + (4 * i + rr) * 128 + 4 * j);
    r[rr][0] = v.x; r[rr][1] = v.y; r[rr][2] = v.z; r[rr][3] = v.w;
  }
  float e = 0.f;
  float ll1[2][2];
  size_t b0 = (size_t)bc * 3 * 4096;
#pragma unroll
  for (int a = 0; a < 2; ++a)
#pragma unroll
    for (int b = 0; b < 2; ++b) {
      float x00 = r[2*a][2*b], x01 = r[2*a][2*b+1];
      float x10 = r[2*a+1][2*b], x11 = r[2*a+1][2*b+1];
      float ll = 0.5f * (x00 + x01 + x10 + x11);
      float lh = 0.5f * (x00 + x01 - x10 - x11);
      float hl = 0.5f * (x00 - x01 + x10 - x11);
      float hh = 0.5f * (x00 - x01 - x10 + x11);
      ll1[a][b] = ll;
      e += lh * lh + hl * hl + hh * hh;
      int pos = (2*i + a) * 64 + (2*j + b);
      yh0[b0 + pos]        = lh;
      yh0[b0 + 4096 + pos] = hl;
      yh0[b0 + 8192 + pos] = hh;
    }
  float x00 = ll1[0][0], x01 = ll1[0][1], x10 = ll1[1][0], x11 = ll1[1][1];
  float ll2 = 0.5f * (x00 + x01 + x10 + x11);
  float lh2 = 0.5f * (x00 + x01 - x10 - x11);
  float hl2 = 0.5f * (x00 - x01 + x10 - x11);
  float hh2 = 0.5f * (x00 - x01 - x10 + x11);
  e += lh2 * lh2 + hl2 * hl2 + hh2 * hh2;
  qll[idx] = ll2;
  size_t b1 = (size_t)bc * 3 * 1024;
  yh1[b1 + t]        = lh2;
  yh1[b1 + 1024 + t] = hl2;
  yh1[b1 + 2048 + t] = hh2;

  __shared__ float red[256];
  red[threadIdx.x] = e;
  __syncthreads();
  for (int off = 128; off > 0; off >>= 1) {
    if (threadIdx.x < off) red[threadIdx.x] += red[threadIdx.x + off];
    __syncthreads();
  }
  if (threadIdx.x == 0) partial[blockIdx.x] = red[0];
}

// kv: flat j = n*B + b reads key_value_multi[b, n]; output (j, C, 32, 32)
__global__ __launch_bounds__(256) void kvdwt_kernel(const float* __restrict__ kvm,
                                                    float* __restrict__ ll) {
  int idx = blockIdx.x * 256 + threadIdx.x;   // < 8*256*1024
  int bc = idx >> 10;      // j*256 + c
  int t  = idx & 1023;
  int i = t >> 5, j2 = t & 31;
  int jj = bc >> 8, c = bc & 255;
  int n = jj >> 1, b = jj & 1;
  const float* xp = kvm + ((size_t)(b * 4 + n) * 256 + c) * 16384;
  float s = 0.f;
#pragma unroll
  for (int rr = 0; rr < 4; ++rr) {
    float4 v = *reinterpret_cast<const float4*>(xp + (4 * i + rr) * 128 + 4 * j2);
    s += (v.x + v.y) + (v.z + v.w);
  }
  ll[idx] = 0.25f * s;
}

// --- conv helpers ------------------------------------------------------
static __device__ __forceinline__ void stage_w_tile(const float* __restrict__ Wm,
    char* ldsA, int o0, int k0, int oA, int kqA) {
  const float* wp = Wm + (size_t)(o0 + oA) * 256 + k0 + kqA;
  float4 w0 = *reinterpret_cast<const float4*>(wp);
  float4 w1 = *reinterpret_cast<const float4*>(wp + 4);
  float4 w2 = *reinterpret_cast<const float4*>(wp + 8);
  float4 w3 = *reinterpret_cast<const float4*>(wp + 12);
  union { s16x8 v; unsigned u[4]; } a0, a1;
  a0.u[0] = pack2(w0.x, w0.y); a0.u[1] = pack2(w0.z, w0.w);
  a0.u[2] = pack2(w1.x, w1.y); a0.u[3] = pack2(w1.z, w1.w);
  a1.u[0] = pack2(w2.x, w2.y); a1.u[1] = pack2(w2.z, w2.w);
  a1.u[2] = pack2(w3.x, w3.y); a1.u[3] = pack2(w3.z, w3.w);
  int byte0 = oA * 128 + kqA * 2;
  *reinterpret_cast<s16x8*>(ldsA + swz(byte0))      = a0.v;
  *reinterpret_cast<s16x8*>(ldsA + swz(byte0 + 16)) = a1.v;
}

static __device__ __forceinline__ void stage_x_tile(const float* __restrict__ Xp,
    char* ldsB, int k0, int t0, int tB, int kg0) {
#pragma unroll
  for (int rep = 0; rep < 2; ++rep) {
    int kg = kg0 + rep * 4;
    const float* xp = Xp + (size_t)(k0 + kg * 8) * 1024 + t0 + tB;
    float v0 = xp[0];
    float v1 = xp[1024];
    float v2 = xp[2048];
    float v3 = xp[3072];
    float v4 = xp[4096];
    float v5 = xp[5120];
    float v6 = xp[6144];
    float v7 = xp[7168];
    union { s16x8 v; unsigned u[4]; } b;
    b.u[0] = pack2(v0, v1); b.u[1] = pack2(v2, v3);
    b.u[2] = pack2(v4, v5); b.u[3] = pack2(v6, v7);
    *reinterpret_cast<s16x8*>(ldsB + swz(tB * 128 + kg * 16)) = b.v;
  }
}

// staging with mean over 4 consecutive j-slices (for the P-conv)
static __device__ __forceinline__ void stage_x_tile_m4(const float* __restrict__ Xp,
    char* ldsB, int k0, int t0, int tB, int kg0) {
#pragma unroll
  for (int rep = 0; rep < 2; ++rep) {
    int kg = kg0 + rep * 4;
    const float* xp = Xp + (size_t)(k0 + kg * 8) * 1024 + t0 + tB;
    float vv[8];
#pragma unroll
    for (int d = 0; d < 8; ++d) {
      size_t off = (size_t)d * 1024;
      vv[d] = 0.25f * ((xp[off] + xp[off + 262144]) +
                       (xp[off + 524288] + xp[off + 786432]));
    }
    union { s16x8 v; unsigned u[4]; } b;
    b.u[0] = pack2(vv[0], vv[1]); b.u[1] = pack2(vv[2], vv[3]);
    b.u[2] = pack2(vv[4], vv[5]); b.u[3] = pack2(vv[6], vv[7]);
    *reinterpret_cast<s16x8*>(ldsB + swz(tB * 128 + kg * 16)) = b.v;
  }
}

// ---------------------------------------------------------------------------
// MFMA conv1x1 (single output): tile 64o x 64t, 4 waves (32x32 each), BK=64.
// ---------------------------------------------------------------------------
__global__ __launch_bounds__(256) void conv_s_kernel(const float* __restrict__ X,
    const float* __restrict__ Wm, const float* __restrict__ bias,
    float* __restrict__ Y, int in_mod) {
  const int tid = threadIdx.x;
  const int hi = (tid >> 5) & 1;
  const int ln = tid & 31;
  const int w = tid >> 6;
  const int o_off = (w >> 1) * 32;
  const int t_off = (w & 1) * 32;
  const int t0 = blockIdx.x * 64;
  const int o0 = blockIdx.y * 64;
  const int jj = blockIdx.z;
  const float* Xp = X + (size_t)(jj % in_mod) * 262144;

  __shared__ __align__(16) char lds[16384];
  char* ldsA = lds;
  char* ldsB = lds + 8192;

  f32x16 acc;
#pragma unroll
  for (int r = 0; r < 16; ++r) acc[r] = 0.f;

  const int oA = tid >> 2;
  const int kqA = (tid & 3) * 16;
  const int tB = tid & 63;
  const int kg0 = tid >> 6;

  for (int kk = 0; kk < 4; ++kk) {
    const int k0 = kk * 64;
    stage_w_tile(Wm, ldsA, o0, k0, oA, kqA);
    stage_x_tile(Xp, ldsB, k0, t0, tB, kg0);
    __syncthreads();
#pragma unroll
    for (int ks = 0; ks < 64; ks += 16) {
      s16x8 af = *reinterpret_cast<const s16x8*>(ldsA + swz((o_off + ln) * 128 + ks * 2 + hi * 16));
      s16x8 bf = *reinterpret_cast<const s16x8*>(ldsB + swz((t_off + ln) * 128 + ks * 2 + hi * 16));
      acc = __builtin_amdgcn_mfma_f32_32x32x16_bf16(af, bf, acc, 0, 0, 0);
    }
    __syncthreads();
  }

  size_t ybase = ((size_t)jj * 256 + o0) * 1024 + t0;
#pragma unroll
  for (int r = 0; r < 16; ++r) {
    int o = o_off + (r & 3) + 8 * (r >> 2) + 4 * hi;
    Y[ybase + (size_t)o * 1024 + t_off + ln] = acc[r] + bias[o0 + o];
  }
}

// ---------------------------------------------------------------------------
// MFMA conv1x1 with fused mean over 4 j-slices: Y[bp] = Wp * mean_n X[bp*4+n]
// ---------------------------------------------------------------------------
__global__ __launch_bounds__(256) void conv_pm_kernel(const float* __restrict__ X,
    const float* __restrict__ Wm, const float* __restrict__ bias,
    float* __restrict__ Y) {
  const int tid = threadIdx.x;
  const int hi = (tid >> 5) & 1;
  const int ln = tid & 31;
  const int w = tid >> 6;
  const int o_off = (w >> 1) * 32;
  const int t_off = (w & 1) * 32;
  const int t0 = blockIdx.x * 64;
  const int o0 = blockIdx.y * 64;
  const int bp = blockIdx.z;
  const float* Xp = X + (size_t)bp * 1048576;   // base of 4 slices

  __shared__ __align__(16) char lds[16384];
  char* ldsA = lds;
  char* ldsB = lds + 8192;

  f32x16 acc;
#pragma unroll
  for (int r = 0; r < 16; ++r) acc[r] = 0.f;

  const int oA = tid >> 2;
  const int kqA = (tid & 3) * 16;
  const int tB = tid & 63;
  const int kg0 = tid >> 6;

  for (int kk = 0; kk < 4; ++kk) {
    const int k0 = kk * 64;
    stage_w_tile(Wm, ldsA, o0, k0, oA, kqA);
    stage_x_tile_m4(Xp, ldsB, k0, t0, tB, kg0);
    __syncthreads();
#pragma unroll
    for (int ks = 0; ks < 64; ks += 16) {
      s16x8 af = *reinterpret_cast<const s16x8*>(ldsA + swz((o_off + ln) * 128 + ks * 2 + hi * 16));
      s16x8 bf = *reinterpret_cast<const s16x8*>(ldsB + swz((t_off + ln) * 128 + ks * 2 + hi * 16));
      acc = __builtin_amdgcn_mfma_f32_32x32x16_bf16(af, bf, acc, 0, 0, 0);
    }
    __syncthreads();
  }

  size_t ybase = ((size_t)bp * 256 + o0) * 1024 + t0;
#pragma unroll
  for (int r = 0; r < 16; ++r) {
    int o = o_off + (r & 3) + 8 * (r >> 2) + 4 * hi;
    Y[ybase + (size_t)o * 1024 + t_off + ln] = acc[r] + bias[o0 + o];
  }
}

// ---------------------------------------------------------------------------
// MFMA conv1x1 (dual output, shared X staging): Yk = Wk X + bk, Yv = Wv X + bv
// ---------------------------------------------------------------------------
__global__ __launch_bounds__(256) void conv_d_kernel(const float* __restrict__ X,
    const float* __restrict__ Wk, const float* __restrict__ bk,
    const float* __restrict__ Wv, const float* __restrict__ bv,
    float* __restrict__ Yk, float* __restrict__ Yv) {
  const int tid = threadIdx.x;
  const int hi = (tid >> 5) & 1;
  const int ln = tid & 31;
  const int w = tid >> 6;
  const int o_off = (w >> 1) * 32;
  const int t_off = (w & 1) * 32;
  const int t0 = blockIdx.x * 64;
  const int o0 = blockIdx.y * 64;
  const int jj = blockIdx.z;
  const float* Xp = X + (size_t)jj * 262144;

  __shared__ __align__(16) char lds[24576];
  char* ldsAk = lds;
  char* ldsAv = lds + 8192;
  char* ldsB  = lds + 16384;

  f32x16 acck, accv;
#pragma unroll
  for (int r = 0; r < 16; ++r) { acck[r] = 0.f; accv[r] = 0.f; }

  const int oA = tid >> 2;
  const int kqA = (tid & 3) * 16;
  const int tB = tid & 63;
  const int kg0 = tid >> 6;

  for (int kk = 0; kk < 4; ++kk) {
    const int k0 = kk * 64;
    stage_w_tile(Wk, ldsAk, o0, k0, oA, kqA);
    stage_w_tile(Wv, ldsAv, o0, k0, oA, kqA);
    stage_x_tile(Xp, ldsB, k0, t0, tB, kg0);
    __syncthreads();
#pragma unroll
    for (int ks = 0; ks < 64; ks += 16) {
      s16x8 bf  = *reinterpret_cast<const s16x8*>(ldsB  + swz((t_off + ln) * 128 + ks * 2 + hi * 16));
      s16x8 afk = *reinterpret_cast<const s16x8*>(ldsAk + swz((o_off + ln) * 128 + ks * 2 + hi * 16));
      s16x8 afv = *reinterpret_cast<const s16x8*>(ldsAv + swz((o_off + ln) * 128 + ks * 2 + hi * 16));
      acck = __builtin_amdgcn_mfma_f32_32x32x16_bf16(afk, bf, acck, 0, 0, 0);
      accv = __builtin_amdgcn_mfma_f32_32x32x16_bf16(afv, bf, accv, 0, 0, 0);
    }
    __syncthreads();
  }

  size_t ybase = ((size_t)jj * 256 + o0) * 1024 + t0;
#pragma unroll
  for (int r = 0; r < 16; ++r) {
    int o = o_off + (r & 3) + 8 * (r >> 2) + 4 * hi;
    Yk[ybase + (size_t)o * 1024 + t_off + ln] = acck[r] + bk[o0 + o];
    Yv[ybase + (size_t)o * 1024 + t_off + ln] = accv[r] + bv[o0 + o];
  }
}

// ---------------------------------------------------------------------------
// MFMA flash attention, 4 waves/block sharing LDS-staged K/V tiles.
// (unchanged from round 3)
// ---------------------------------------------------------------------------
__global__ __launch_bounds__(256) void attn_mfma_kernel(const float* __restrict__ qb,
    const float* __restrict__ kb, const float* __restrict__ vb,
    float* __restrict__ ao) {
  const int tid = threadIdx.x;
  const int w   = tid >> 6;
  const int hi  = (tid >> 5) & 1;
  const int ln  = tid & 31;
  const int jh  = blockIdx.x >> 3;
  const int qg  = blockIdx.x & 7;
  const int qbase = (qg * 4 + w) * 32;
  const size_t base = (size_t)jh * 32768;
  const int j = jh >> 3, h = jh & 7;
  const float* qp = qb + (size_t)((j & 1) * 8 + h) * 32768;
  const float* kp = kb + base;
  const float* vp = vb + base;

  __shared__ unsigned KpL[2][544];
  __shared__ unsigned VpL[2][544];
  __shared__ float tileT[4][1056];

  const int sdp = tid >> 5;
  const int st  = tid & 31;
  const int svd = tid >> 4;
  const int svt = tid & 15;

  s16x8 Qf[2];
#pragma unroll
  for (int c = 0; c < 2; ++c) {
    union { s16x8 v; unsigned u[4]; } u;
#pragma unroll
    for (int e2 = 0; e2 < 4; ++e2) {
      int d = c * 16 + hi * 8 + e2 * 2;
      float a = qp[(size_t)d * 1024 + qbase + ln]       * 0.17677669529663687f;
      float b = qp[(size_t)(d + 1) * 1024 + qbase + ln] * 0.17677669529663687f;
      u.u[e2] = pack2(a, b);
    }
    Qf[c] = u.v;
  }

  f32x16 acc;
#pragma unroll
  for (int r = 0; r < 16; ++r) acc[r] = 0.f;
  float m = -1e30f, lsum = 0.f;

  {
    float ka0 = kp[(size_t)(2 * sdp) * 1024 + st];
    float kb0v = kp[(size_t)(2 * sdp + 1) * 1024 + st];
    float ka1 = kp[(size_t)(2 * (sdp + 8)) * 1024 + st];
    float kb1v = kp[(size_t)(2 * (sdp + 8) + 1) * 1024 + st];
    float2 v0 = *reinterpret_cast<const float2*>(vp + (size_t)svd * 1024 + 2 * svt);
    float2 v1 = *reinterpret_cast<const float2*>(vp + (size_t)(svd + 16) * 1024 + 2 * svt);
    KpL[0][st * 17 + sdp]     = pack2(ka0, kb0v);
    KpL[0][st * 17 + sdp + 8] = pack2(ka1, kb1v);
    VpL[0][svd * 17 + svt]        = pack2(v0.x, v0.y);
    VpL[0][(svd + 16) * 17 + svt] = pack2(v1.x, v1.y);
  }
  __syncthreads();

  for (int tile = 0; tile < 32; ++tile) {
    const int cur = tile & 1;
    float nka0 = 0.f, nkb0 = 0.f, nka1 = 0.f, nkb1 = 0.f;
    float2 nv0 = make_float2(0.f, 0.f), nv1 = make_float2(0.f, 0.f);
    if (tile < 31) {
      const int kn = (tile + 1) * 32;
      nka0 = kp[(size_t)(2 * sdp) * 1024 + kn + st];
      nkb0 = kp[(size_t)(2 * sdp + 1) * 1024 + kn + st];
      nka1 = kp[(size_t)(2 * (sdp + 8)) * 1024 + kn + st];
      nkb1 = kp[(size_t)(2 * (sdp + 8) + 1) * 1024 + kn + st];
      nv0 = *reinterpret_cast<const float2*>(vp + (size_t)svd * 1024 + kn + 2 * svt);
      nv1 = *reinterpret_cast<const float2*>(vp + (size_t)(svd + 16) * 1024 + kn + 2 * svt);
    }

    s16x8 Kf[2];
#pragma unroll
    for (int c = 0; c < 2; ++c) {
      union { s16x8 v; unsigned u[4]; } u;
#pragma unroll
      for (int e = 0; e < 4; ++e)
        u.u[e] = KpL[cur][ln * 17 + c * 8 + hi * 4 + e];
      Kf[c] = u.v;
    }
    f32x16 S;
#pragma unroll
    for (int r = 0; r < 16; ++r) S[r] = 0.f;
    S = __builtin_amdgcn_mfma_f32_32x32x16_bf16(Kf[0], Qf[0], S, 0, 0, 0);
    S = __builtin_amdgcn_mfma_f32_32x32x16_bf16(Kf[1], Qf[1], S, 0, 0, 0);

    float tmax = S[0];
#pragma unroll
    for (int r = 1; r < 16; ++r) tmax = fmaxf(tmax, S[r]);
    tmax = fmaxf(tmax, __shfl_xor(tmax, 32));
    if (__any(tmax > m + 6.f)) {
      float nm = fmaxf(m, tmax);
      float f  = __expf(m - nm);
      m = nm;
      lsum *= f;
      int fi = __float_as_int(f);
#pragma unroll
      for (int r = 0; r < 16; ++r) {
        int row = (r & 3) + 8 * (r >> 2) + 4 * hi;
        float fr = __int_as_float(__builtin_amdgcn_ds_bpermute(row * 4, fi));
        acc[r] *= fr;
      }
    }
    float p[16];
#pragma unroll
    for (int r = 0; r < 16; ++r) {
      p[r] = __expf(S[r] - m);
      lsum += p[r];
    }
    unsigned P[8];
#pragma unroll
    for (int i = 0; i < 8; ++i) P[i] = pack2(p[2 * i], p[2 * i + 1]);

#pragma unroll
    for (int c = 0; c < 2; ++c) {
      unsigned p0 = P[4 * c + 0], p1 = P[4 * c + 1];
      unsigned p2 = P[4 * c + 2], p3 = P[4 * c + 3];
      unsigned s0 = (unsigned)__shfl_xor((int)p0, 32);
      unsigned s1 = (unsigned)__shfl_xor((int)p1, 32);
      unsigned s2 = (unsigned)__shfl_xor((int)p2, 32);
      unsigned s3 = (unsigned)__shfl_xor((int)p3, 32);
      union { s16x8 v; unsigned u[4]; } pa;
      pa.u[0] = hi ? s2 : p0;
      pa.u[1] = hi ? s3 : p1;
      pa.u[2] = hi ? p2 : s0;
      pa.u[3] = hi ? p3 : s1;
      union { s16x8 v; unsigned u[4]; } vf;
#pragma unroll
      for (int e = 0; e < 4; ++e)
        vf.u[e] = VpL[cur][ln * 17 + c * 8 + hi * 4 + e];
      acc = __builtin_amdgcn_mfma_f32_32x32x16_bf16(pa.v, vf.v, acc, 0, 0, 0);
    }

    if (tile < 31) {
      const int nxt = cur ^ 1;
      KpL[nxt][st * 17 + sdp]     = pack2(nka0, nkb0);
      KpL[nxt][st * 17 + sdp + 8] = pack2(nka1, nkb1);
      VpL[nxt][svd * 17 + svt]        = pack2(nv0.x, nv0.y);
      VpL[nxt][(svd + 16) * 17 + svt] = pack2(nv1.x, nv1.y);
    }
    __syncthreads();
  }

  float ltot = lsum + __shfl_xor(lsum, 32);
  float inv  = 1.f / ltot;

  float* tw = tileT[w];
#pragma unroll
  for (int r = 0; r < 16; ++r) {
    int row = (r & 3) + 8 * (r >> 2) + 4 * hi;
    tw[row * 33 + ln] = acc[r];
  }
  __syncthreads();
#pragma unroll
  for (int pass = 0; pass < 16; ++pass) {
    int d = pass * 2 + hi;
    float v = tw[ln * 33 + d] * inv;
    ao[base + (size_t)d * 1024 + qbase + ln] = v;
  }
}

// per-group stats from mb + band-energy partials (orthonormal Haar identity)
__global__ __launch_bounds__(256) void stats64_kernel(const float* __restrict__ mb,
    const float* __restrict__ partial, float* __restrict__ stats) {
  int g = blockIdx.x, tid = threadIdx.x;
  const float4* p = reinterpret_cast<const float4*>(
      mb + (size_t)(g >> 5) * 262144 + (size_t)(g & 31) * 8192);
  float s = 0.f, s2 = 0.f;
  for (int e = tid; e < 2048; e += 256) {
    float4 v = p[e];
    s  += (v.x + v.y) + (v.z + v.w);
    s2 += (v.x * v.x + v.y * v.y) + (v.z * v.z + v.w * v.w);
  }
  if (tid < 32) {
    int cc = tid >> 2, q = tid & 3;
    s2 += partial[(((g >> 5) * 256 + (g & 31) * 8 + cc) << 2) + q];
  }
  __shared__ float ls[256], ls2[256];
  ls[tid] = s; ls2[tid] = s2;
  __syncthreads();
  for (int off = 128; off > 0; off >>= 1) {
    if (tid < off) { ls[tid] += ls[tid + off]; ls2[tid] += ls2[tid + off]; }
    __syncthreads();
  }
  if (tid == 0) {
    float mean = 4.f * ls[0] * (1.f / 131072.f);
    float ex2  = ls2[0] * (1.f / 131072.f);
    float var  = ex2 - mean * mean;
    stats[g * 2]     = mean;
    stats[g * 2 + 1] = rsqrtf(var + 1e-5f);
  }
}

// fused: both IDWT levels + GroupNorm + residual, one pass.
// thread -> one (bc, i, j) ll2 cell -> 4x4 output block.
__global__ __launch_bounds__(256) void idwt_gn_kernel(const float* __restrict__ mb,
    const float* __restrict__ yh1, const float* __restrict__ yh0,
    const float* __restrict__ query, const float* __restrict__ stats,
    const float* __restrict__ gamma, const float* __restrict__ beta,
    float* __restrict__ out) {
  int idx = blockIdx.x * 256 + threadIdx.x;   // < 524288
  int bc = idx >> 10;
  int t  = idx & 1023;
  int i = t >> 5, j = t & 31;
  int c = bc & 255;
  int g = (bc >> 8) * 32 + (c >> 3);
  float mean = stats[2 * g], rstd = stats[2 * g + 1];
  float ga = gamma[c], be = beta[c];

  float v = mb[idx];
  const float* y1 = yh1 + (size_t)bc * 3072 + t;
  float lh = y1[0], hl = y1[1024], hh = y1[2048];
  float a  = v + lh, b2 = v - lh;
  float c2 = hl + hh, d2 = hl - hh;
  float idv[2][2];
  idv[0][0] = 0.5f * (a + c2);  idv[0][1] = 0.5f * (a - c2);
  idv[1][0] = 0.5f * (b2 + d2); idv[1][1] = 0.5f * (b2 - d2);

  const float* y0 = yh0 + (size_t)bc * 12288;
  const float* qp = query + (size_t)bc * 16384;
  float* op = out + (size_t)bc * 16384;

#pragma unroll
  for (int a2 = 0; a2 < 2; ++a2) {
    int I = 2 * i + a2;
    float2 lh0 = *reinterpret_cast<const float2*>(y0 +        I * 64 + 2 * j);
    float2 hl0 = *reinterpret_cast<const float2*>(y0 + 4096 + I * 64 + 2 * j);
    float2 hh0 = *reinterpret_cast<const float2*>(y0 + 8192 + I * 64 + 2 * j);
    float r0[4], r1[4];
#pragma unroll
    for (int b3 = 0; b3 < 2; ++b3) {
      float ll = idv[a2][b3];
      float l0 = b3 ? lh0.y : lh0.x;
      float h0 = b3 ? hl0.y : hl0.x;
      float x0 = b3 ? hh0.y : hh0.x;
      float aa = ll + l0, bb = ll - l0;
      float cc = h0 + x0, dd = h0 - x0;
      r0[2 * b3]     = 0.5f * (aa + cc);
      r0[2 * b3 + 1] = 0.5f * (aa - cc);
      r1[2 * b3]     = 0.5f * (bb + dd);
      r1[2 * b3 + 1] = 0.5f * (bb - dd);
    }
    int off0 = (2 * I) * 128 + 4 * j;
    float4 q0 = *reinterpret_cast<const float4*>(qp + off0);
    float4 q1 = *reinterpret_cast<const float4*>(qp + off0 + 128);
    float4 o0, o1;
    o0.x = (r0[0] - mean) * rstd * ga + be + q0.x;
    o0.y = (r0[1] - mean) * rstd * ga + be + q0.y;
    o0.z = (r0[2] - mean) * rstd * ga + be + q0.z;
    o0.w = (r0[3] - mean) * rstd * ga + be + q0.w;
    o1.x = (r1[0] - mean) * rstd * ga + be + q1.x;
    o1.y = (r1[1] - mean) * rstd * ga + be + q1.y;
    o1.z = (r1[2] - mean) * rstd * ga + be + q1.z;
    o1.w = (r1[3] - mean) * rstd * ga + be + q1.w;
    *reinterpret_cast<float4*>(op + off0)       = o0;
    *reinterpret_cast<float4*>(op + off0 + 128) = o1;
  }
}

extern "C" void kernel_launch(void* const* d_in, const int* in_sizes, int n_in,
                              void* d_out, int out_size, void* d_ws, size_t ws_size,
                              hipStream_t stream) {
  const float* query = (const float*)d_in[0];
  const float* kvm   = (const float*)d_in[1];
  // d_in[2] = value_multi: unused by the reference
  const float* Wq = (const float*)d_in[3];
  const float* bq = (const float*)d_in[4];
  const float* Wk = (const float*)d_in[5];
  const float* bk = (const float*)d_in[6];
  const float* Wv = (const float*)d_in[7];
  const float* bv = (const float*)d_in[8];
  const float* Wp = (const float*)d_in[9];
  const float* bp = (const float*)d_in[10];
  const float* gamma = (const float*)d_in[11];
  const float* beta  = (const float*)d_in[12];
  float* out = (float*)d_out;
  float* ws  = (float*)d_ws;

  if (ws_size < (size_t)17827968 * 4) return;  // insufficient scratch

  float* qll     = ws;                    // 524288
  float* yh0     = qll  + 524288;         // 6291456
  float* yh1     = yh0  + 6291456;        // 1572864
  float* kvll    = yh1  + 1572864;        // 2097152
  float* qb      = kvll + 2097152;        // 524288 (j=0,1 only)
  float* kb      = qb   + 524288;         // 2097152
  float* vb      = kb   + 2097152;        // 2097152
  float* ao      = vb   + 2097152;        // 2097152
  float* mb      = ao   + 2097152;        // 524288
  float* partial = mb   + 524288;         // 2048
  float* stats   = partial + 2048;        // 128

  qdwt_kernel<<<2048, 256, 0, stream>>>(query, qll, yh0, yh1, partial);
  kvdwt_kernel<<<8192, 256, 0, stream>>>(kvm, kvll);

  conv_s_kernel<<<dim3(16, 4, 2), 256, 0, stream>>>(qll, Wq, bq, qb, 2);
  conv_d_kernel<<<dim3(16, 4, 8), 256, 0, stream>>>(kvll, Wk, bk, Wv, bv, kb, vb);

  attn_mfma_kernel<<<512, 256, 0, stream>>>(qb, kb, vb, ao);

  conv_pm_kernel<<<dim3(16, 4, 2), 256, 0, stream>>>(ao, Wp, bp, mb);
  stats64_kernel<<<64, 256, 0, stream>>>(mb, partial, stats);

  idwt_gn_kernel<<<2048, 256, 0, stream>>>(mb, yh1, yh0, query, stats,
                                           gamma, beta, out);
}

// Round 6
// 96.597 us; speedup vs baseline: 8.1642x; 1.2424x over previous
//
#include <hip/hip_runtime.h>

// B=2, N=4, C=256, H=W=128, J=2, heads=8, hd=32, T=1024
// Key algebra: idwt is linear and Haar is orthonormal =>
//   out_full = query + upsample4(0.25*(mb - qll))
//   sum(out_full) = 4*sum(mb);  sum(out_full^2) = sum(query^2) + sum(mb^2) - sum(qll^2)
// so the yh band buffers are never materialized.
// ws (float units): qll(bf16) 262144 | kvll(bf16) 1048576 | qbp(u32) 262144 |
//   kbp(u32) 1048576 | vb(bf16) 1048576 | aop(u32) 1048576 | mb 524288 |
//   partial 2048 | stats 128  => 5,244,032 floats (21 MB)

typedef float f32x16 __attribute__((ext_vector_type(16)));
typedef short s16x8 __attribute__((ext_vector_type(8)));

static __device__ __forceinline__ unsigned f2bf_bits(float x) {
  unsigned u = __float_as_uint(x);
  return (u + 0x7fffu + ((u >> 16) & 1u)) >> 16;
}
static __device__ __forceinline__ unsigned pack2(float a, float b) {
  return f2bf_bits(a) | (f2bf_bits(b) << 16);
}
static __device__ __forceinline__ float bflo(unsigned u) {
  return __uint_as_float(u << 16);
}
static __device__ __forceinline__ float bfhi(unsigned u) {
  return __uint_as_float(u & 0xffff0000u);
}
// XOR-swizzle for 128B-row LDS tiles: slot bits [6:4] ^= row bits [9:7]
static __device__ __forceinline__ int swz(int byte) {
  return byte ^ (((byte >> 7) & 7) << 4);
}

// Merged DWT: blocks [0,2048) = query (ll2 + per-block sum(query^2));
// blocks [2048,10240) = kv ll2.
__global__ __launch_bounds__(256) void dwt_kernel(const float* __restrict__ query,
    const float* __restrict__ kvm, unsigned short* __restrict__ qll,
    unsigned short* __restrict__ kvll, float* __restrict__ partial) {
  int bid = blockIdx.x;
  if (bid < 2048) {
    int idx = bid * 256 + threadIdx.x;     // < 524288
    int bc = idx >> 10;
    int t  = idx & 1023;
    int i = t >> 5, j = t & 31;
    const float* xp = query + (size_t)bc * 16384;
    float s = 0.f, e = 0.f;
#pragma unroll
    for (int rr = 0; rr < 4; ++rr) {
      float4 v = *reinterpret_cast<const float4*>(xp + (4 * i + rr) * 128 + 4 * j);
      s += (v.x + v.y) + (v.z + v.w);
      e += (v.x * v.x + v.y * v.y) + (v.z * v.z + v.w * v.w);
    }
    qll[idx] = (unsigned short)f2bf_bits(0.25f * s);
    __shared__ float red[256];
    red[threadIdx.x] = e;
    __syncthreads();
    for (int off = 128; off > 0; off >>= 1) {
      if (threadIdx.x < off) red[threadIdx.x] += red[threadIdx.x + off];
      __syncthreads();
    }
    if (threadIdx.x == 0) partial[bid] = red[0];
  } else {
    int idx = (bid - 2048) * 256 + threadIdx.x;   // < 2097152
    int bc = idx >> 10;      // j*256 + c
    int t  = idx & 1023;
    int i = t >> 5, j2 = t & 31;
    int jj = bc >> 8, c = bc & 255;
    int n = jj >> 1, b = jj & 1;
    const float* xp = kvm + ((size_t)(b * 4 + n) * 256 + c) * 16384;
    float s = 0.f;
#pragma unroll
    for (int rr = 0; rr < 4; ++rr) {
      float4 v = *reinterpret_cast<const float4*>(xp + (4 * i + rr) * 128 + 4 * j2);
      s += (v.x + v.y) + (v.z + v.w);
    }
    kvll[idx] = (unsigned short)f2bf_bits(0.25f * s);
  }
}

// --- conv staging helpers ---------------------------------------------
static __device__ __forceinline__ void stage_w(const float* __restrict__ Wm,
    char* ldsA, int o0, int k0, int oA, int kqA, float sc) {
  const float* wp = Wm + (size_t)(o0 + oA) * 256 + k0 + kqA;
  float4 w0 = *reinterpret_cast<const float4*>(wp);
  float4 w1 = *reinterpret_cast<const float4*>(wp + 4);
  float4 w2 = *reinterpret_cast<const float4*>(wp + 8);
  float4 w3 = *reinterpret_cast<const float4*>(wp + 12);
  union { s16x8 v; unsigned u[4]; } a0, a1;
  a0.u[0] = pack2(sc * w0.x, sc * w0.y); a0.u[1] = pack2(sc * w0.z, sc * w0.w);
  a0.u[2] = pack2(sc * w1.x, sc * w1.y); a0.u[3] = pack2(sc * w1.z, sc * w1.w);
  a1.u[0] = pack2(sc * w2.x, sc * w2.y); a1.u[1] = pack2(sc * w2.z, sc * w2.w);
  a1.u[2] = pack2(sc * w3.x, sc * w3.y); a1.u[3] = pack2(sc * w3.z, sc * w3.w);
  int byte0 = oA * 128 + kqA * 2;
  *reinterpret_cast<s16x8*>(ldsA + swz(byte0))      = a0.v;
  *reinterpret_cast<s16x8*>(ldsA + swz(byte0 + 16)) = a1.v;
}

// X is bf16 [c][t] (ushort); pack k-pairs into u32.
static __device__ __forceinline__ void stage_x_bf(const unsigned short* __restrict__ Xp,
    char* ldsB, int k0, int t0, int tB, int kg0) {
#pragma unroll
  for (int rep = 0; rep < 2; ++rep) {
    int kg = kg0 + rep * 4;
    const unsigned short* xp = Xp + (size_t)(k0 + kg * 8) * 1024 + t0 + tB;
    union { s16x8 v; unsigned u[4]; } b;
#pragma unroll
    for (int e2 = 0; e2 < 4; ++e2) {
      unsigned lo = xp[(size_t)(2 * e2) * 1024];
      unsigned hi2 = xp[(size_t)(2 * e2 + 1) * 1024];
      b.u[e2] = lo | (hi2 << 16);
    }
    *reinterpret_cast<s16x8*>(ldsB + swz(tB * 128 + kg * 16)) = b.v;
  }
}

// A is paired-bf16 [cpair][t] (u32); mean over 4 j-slices (stride 131072 u32).
static __device__ __forceinline__ void stage_x_m4p(const unsigned* __restrict__ Ap,
    char* ldsB, int k0, int t0, int tB, int kg0) {
#pragma unroll
  for (int rep = 0; rep < 2; ++rep) {
    int kg = kg0 + rep * 4;
    const unsigned* xp = Ap + (size_t)(k0 / 2 + kg * 4) * 1024 + t0 + tB;
    union { s16x8 v; unsigned u[4]; } b;
#pragma unroll
    for (int e2 = 0; e2 < 4; ++e2) {
      unsigned a0 = xp[(size_t)e2 * 1024];
      unsigned a1 = xp[(size_t)e2 * 1024 + 131072];
      unsigned a2 = xp[(size_t)e2 * 1024 + 262144];
      unsigned a3 = xp[(size_t)e2 * 1024 + 393216];
      float lo = 0.25f * ((bflo(a0) + bflo(a1)) + (bflo(a2) + bflo(a3)));
      float hi2 = 0.25f * ((bfhi(a0) + bfhi(a1)) + (bfhi(a2) + bfhi(a3)));
      b.u[e2] = pack2(lo, hi2);
    }
    *reinterpret_cast<s16x8*>(ldsB + swz(tB * 128 + kg * 16)) = b.v;
  }
}

// ---------------------------------------------------------------------------
// Fused QKV conv: z<2 -> q (scaled Wq, paired out qbp); z>=2 -> kv dual
// (Wk->kbp paired, Wv->vb plain bf16). Tile 64o x 64t, 4 waves, BK=64.
// ---------------------------------------------------------------------------
__global__ __launch_bounds__(256) void conv_qkv_kernel(
    const unsigned short* __restrict__ qll, const unsigned short* __restrict__ kvll,
    const float* __restrict__ Wq, const float* __restrict__ bq,
    const float* __restrict__ Wk, const float* __restrict__ bk,
    const float* __restrict__ Wv, const float* __restrict__ bv,
    unsigned* __restrict__ qbp, unsigned* __restrict__ kbp,
    unsigned short* __restrict__ vb) {
  const int tid = threadIdx.x;
  const int hi = (tid >> 5) & 1;
  const int ln = tid & 31;
  const int w = tid >> 6;
  const int o_off = (w >> 1) * 32;
  const int t_off = (w & 1) * 32;
  const int t0 = blockIdx.x * 64;
  const int o0 = blockIdx.y * 64;
  const int z = blockIdx.z;

  __shared__ __align__(16) char lds[24576];
  char* ldsA  = lds;
  char* ldsA2 = lds + 8192;
  char* ldsB  = lds + 16384;

  const int oA = tid >> 2;
  const int kqA = (tid & 3) * 16;
  const int tB = tid & 63;
  const int kg0 = tid >> 6;

  if (z < 2) {
    const float S = 0.17677669529663687f;   // hd^-0.5 folded into Wq, bq
    const unsigned short* Xp = qll + (size_t)z * 262144;
    f32x16 acc;
#pragma unroll
    for (int r = 0; r < 16; ++r) acc[r] = 0.f;
    for (int kk = 0; kk < 4; ++kk) {
      const int k0 = kk * 64;
      stage_w(Wq, ldsA, o0, k0, oA, kqA, S);
      stage_x_bf(Xp, ldsB, k0, t0, tB, kg0);
      __syncthreads();
#pragma unroll
      for (int ks = 0; ks < 64; ks += 16) {
        s16x8 af = *reinterpret_cast<const s16x8*>(ldsA + swz((o_off + ln) * 128 + ks * 2 + hi * 16));
        s16x8 bf = *reinterpret_cast<const s16x8*>(ldsB + swz((t_off + ln) * 128 + ks * 2 + hi * 16));
        acc = __builtin_amdgcn_mfma_f32_32x32x16_bf16(af, bf, acc, 0, 0, 0);
      }
      __syncthreads();
    }
    unsigned* Yp = qbp + (size_t)z * 131072;
#pragma unroll
    for (int r = 0; r < 16; r += 2) {
      int o = o_off + (r & 3) + 8 * (r >> 2) + 4 * hi;    // even
      float b0 = S * bq[o0 + o], b1 = S * bq[o0 + o + 1];
      Yp[(size_t)((o0 + o) >> 1) * 1024 + t0 + t_off + ln] =
          pack2(acc[r] + b0, acc[r + 1] + b1);
    }
  } else {
    const int jj = z - 2;
    const unsigned short* Xp = kvll + (size_t)jj * 262144;
    f32x16 acck, accv;
#pragma unroll
    for (int r = 0; r < 16; ++r) { acck[r] = 0.f; accv[r] = 0.f; }
    for (int kk = 0; kk < 4; ++kk) {
      const int k0 = kk * 64;
      stage_w(Wk, ldsA,  o0, k0, oA, kqA, 1.f);
      stage_w(Wv, ldsA2, o0, k0, oA, kqA, 1.f);
      stage_x_bf(Xp, ldsB, k0, t0, tB, kg0);
      __syncthreads();
#pragma unroll
      for (int ks = 0; ks < 64; ks += 16) {
        s16x8 bf  = *reinterpret_cast<const s16x8*>(ldsB  + swz((t_off + ln) * 128 + ks * 2 + hi * 16));
        s16x8 afk = *reinterpret_cast<const s16x8*>(ldsA  + swz((o_off + ln) * 128 + ks * 2 + hi * 16));
        s16x8 afv = *reinterpret_cast<const s16x8*>(ldsA2 + swz((o_off + ln) * 128 + ks * 2 + hi * 16));
        acck = __builtin_amdgcn_mfma_f32_32x32x16_bf16(afk, bf, acck, 0, 0, 0);
        accv = __builtin_amdgcn_mfma_f32_32x32x16_bf16(afv, bf, accv, 0, 0, 0);
      }
      __syncthreads();
    }
    unsigned* Yk = kbp + (size_t)jj * 131072;
    unsigned short* Yv = vb + (size_t)jj * 262144;
#pragma unroll
    for (int r = 0; r < 16; r += 2) {
      int o = o_off + (r & 3) + 8 * (r >> 2) + 4 * hi;
      Yk[(size_t)((o0 + o) >> 1) * 1024 + t0 + t_off + ln] =
          pack2(acck[r] + bk[o0 + o], acck[r + 1] + bk[o0 + o + 1]);
    }
#pragma unroll
    for (int r = 0; r < 16; ++r) {
      int o = o_off + (r & 3) + 8 * (r >> 2) + 4 * hi;
      Yv[(size_t)(o0 + o) * 1024 + t0 + t_off + ln] =
          (unsigned short)f2bf_bits(accv[r] + bv[o0 + o]);
    }
  }
}

// ---------------------------------------------------------------------------
// MFMA flash attention. Inputs pre-paired bf16: qbp/kbp [dpair][t] u32
// (q pre-scaled), vb [d][t] ushort (u32 load = key-pair). Output aop paired.
// ---------------------------------------------------------------------------
__global__ __launch_bounds__(256) void attn_mfma_kernel(
    const unsigned* __restrict__ qbp, const unsigned* __restrict__ kbp,
    const unsigned short* __restrict__ vb, unsigned* __restrict__ aop) {
  const int tid = threadIdx.x;
  const int w   = tid >> 6;
  const int hi  = (tid >> 5) & 1;
  const int ln  = tid & 31;
  const int jh  = blockIdx.x >> 3;
  const int qg  = blockIdx.x & 7;
  const int qbase = (qg * 4 + w) * 32;
  const int j = jh >> 3, h = jh & 7;
  const unsigned* qp = qbp + (size_t)((j & 1) * 8 + h) * 16384;
  const unsigned* kp = kbp + (size_t)jh * 16384;
  const unsigned short* vp = vb + (size_t)jh * 32768;

  __shared__ unsigned KpL[2][544];
  __shared__ unsigned VpL[2][544];
  __shared__ float tileT[4][1056];

  const int sdp = tid >> 5;   // 0..7
  const int st  = tid & 31;
  const int svd = tid >> 4;   // 0..15
  const int svt = tid & 15;

  s16x8 Qf[2];
#pragma unroll
  for (int c = 0; c < 2; ++c) {
    union { s16x8 v; unsigned u[4]; } u;
#pragma unroll
    for (int e2 = 0; e2 < 4; ++e2)
      u.u[e2] = qp[(size_t)(c * 8 + hi * 4 + e2) * 1024 + qbase + ln];
    Qf[c] = u.v;
  }

  f32x16 acc;
#pragma unroll
  for (int r = 0; r < 16; ++r) acc[r] = 0.f;
  float m = -1e30f, lsum = 0.f;

  {
    KpL[0][st * 17 + sdp]     = kp[(size_t)sdp * 1024 + st];
    KpL[0][st * 17 + sdp + 8] = kp[(size_t)(sdp + 8) * 1024 + st];
    VpL[0][svd * 17 + svt] =
        *reinterpret_cast<const unsigned*>(vp + (size_t)svd * 1024 + 2 * svt);
    VpL[0][(svd + 16) * 17 + svt] =
        *reinterpret_cast<const unsigned*>(vp + (size_t)(svd + 16) * 1024 + 2 * svt);
  }
  __syncthreads();

  for (int tile = 0; tile < 32; ++tile) {
    const int cur = tile & 1;
    unsigned nk0 = 0, nk1 = 0, nv0 = 0, nv1 = 0;
    if (tile < 31) {
      const int kn = (tile + 1) * 32;
      nk0 = kp[(size_t)sdp * 1024 + kn + st];
      nk1 = kp[(size_t)(sdp + 8) * 1024 + kn + st];
      nv0 = *reinterpret_cast<const unsigned*>(vp + (size_t)svd * 1024 + kn + 2 * svt);
      nv1 = *reinterpret_cast<const unsigned*>(vp + (size_t)(svd + 16) * 1024 + kn + 2 * svt);
    }

    s16x8 Kf[2];
#pragma unroll
    for (int c = 0; c < 2; ++c) {
      union { s16x8 v; unsigned u[4]; } u;
#pragma unroll
      for (int e = 0; e < 4; ++e)
        u.u[e] = KpL[cur][ln * 17 + c * 8 + hi * 4 + e];
      Kf[c] = u.v;
    }
    f32x16 S;
#pragma unroll
    for (int r = 0; r < 16; ++r) S[r] = 0.f;
    S = __builtin_amdgcn_mfma_f32_32x32x16_bf16(Kf[0], Qf[0], S, 0, 0, 0);
    S = __builtin_amdgcn_mfma_f32_32x32x16_bf16(Kf[1], Qf[1], S, 0, 0, 0);

    float tmax = S[0];
#pragma unroll
    for (int r = 1; r < 16; ++r) tmax = fmaxf(tmax, S[r]);
    tmax = fmaxf(tmax, __shfl_xor(tmax, 32));
    if (__any(tmax > m + 6.f)) {
      float nm = fmaxf(m, tmax);
      float f  = __expf(m - nm);
      m = nm;
      lsum *= f;
      int fi = __float_as_int(f);
#pragma unroll
      for (int r = 0; r < 16; ++r) {
        int row = (r & 3) + 8 * (r >> 2) + 4 * hi;
        float fr = __int_as_float(__builtin_amdgcn_ds_bpermute(row * 4, fi));
        acc[r] *= fr;
      }
    }
    float p[16];
#pragma unroll
    for (int r = 0; r < 16; ++r) {
      p[r] = __expf(S[r] - m);
      lsum += p[r];
    }
    unsigned P[8];
#pragma unroll
    for (int i = 0; i < 8; ++i) P[i] = pack2(p[2 * i], p[2 * i + 1]);

#pragma unroll
    for (int c = 0; c < 2; ++c) {
      unsigned p0 = P[4 * c + 0], p1 = P[4 * c + 1];
      unsigned p2 = P[4 * c + 2], p3 = P[4 * c + 3];
      unsigned s0 = (unsigned)__shfl_xor((int)p0, 32);
      unsigned s1 = (unsigned)__shfl_xor((int)p1, 32);
      unsigned s2 = (unsigned)__shfl_xor((int)p2, 32);
      unsigned s3 = (unsigned)__shfl_xor((int)p3, 32);
      union { s16x8 v; unsigned u[4]; } pa;
      pa.u[0] = hi ? s2 : p0;
      pa.u[1] = hi ? s3 : p1;
      pa.u[2] = hi ? p2 : s0;
      pa.u[3] = hi ? p3 : s1;
      union { s16x8 v; unsigned u[4]; } vf;
#pragma unroll
      for (int e = 0; e < 4; ++e)
        vf.u[e] = VpL[cur][ln * 17 + c * 8 + hi * 4 + e];
      acc = __builtin_amdgcn_mfma_f32_32x32x16_bf16(pa.v, vf.v, acc, 0, 0, 0);
    }

    if (tile < 31) {
      const int nxt = cur ^ 1;
      KpL[nxt][st * 17 + sdp]     = nk0;
      KpL[nxt][st * 17 + sdp + 8] = nk1;
      VpL[nxt][svd * 17 + svt]        = nv0;
      VpL[nxt][(svd + 16) * 17 + svt] = nv1;
    }
    __syncthreads();
  }

  float ltot = lsum + __shfl_xor(lsum, 32);
  float inv  = 1.f / ltot;

  float* tw = tileT[w];
#pragma unroll
  for (int r = 0; r < 16; ++r) {
    int row = (r & 3) + 8 * (r >> 2) + 4 * hi;
    tw[row * 33 + ln] = acc[r];
  }
  __syncthreads();
  unsigned* aw = aop + (size_t)jh * 16384;
#pragma unroll
  for (int pass = 0; pass < 8; ++pass) {
    int dp = pass * 2 + hi;
    float v0 = tw[ln * 33 + 2 * dp] * inv;
    float v1 = tw[ln * 33 + 2 * dp + 1] * inv;
    aw[(size_t)dp * 1024 + qbase + ln] = pack2(v0, v1);
  }
}

// ---------------------------------------------------------------------------
// P-conv with fused mean over 4 j-slices; input aop paired bf16; out mb fp32.
// ---------------------------------------------------------------------------
__global__ __launch_bounds__(256) void conv_pm_kernel(const unsigned* __restrict__ aop,
    const float* __restrict__ Wm, const float* __restrict__ bias,
    float* __restrict__ Y) {
  const int tid = threadIdx.x;
  const int hi = (tid >> 5) & 1;
  const int ln = tid & 31;
  const int w = tid >> 6;
  const int o_off = (w >> 1) * 32;
  const int t_off = (w & 1) * 32;
  const int t0 = blockIdx.x * 64;
  const int o0 = blockIdx.y * 64;
  const int bp = blockIdx.z;
  const unsigned* Ap = aop + (size_t)bp * 524288;

  __shared__ __align__(16) char lds[16384];
  char* ldsA = lds;
  char* ldsB = lds + 8192;

  f32x16 acc;
#pragma unroll
  for (int r = 0; r < 16; ++r) acc[r] = 0.f;

  const int oA = tid >> 2;
  const int kqA = (tid & 3) * 16;
  const int tB = tid & 63;
  const int kg0 = tid >> 6;

  for (int kk = 0; kk < 4; ++kk) {
    const int k0 = kk * 64;
    stage_w(Wm, ldsA, o0, k0, oA, kqA, 1.f);
    stage_x_m4p(Ap, ldsB, k0, t0, tB, kg0);
    __syncthreads();
#pragma unroll
    for (int ks = 0; ks < 64; ks += 16) {
      s16x8 af = *reinterpret_cast<const s16x8*>(ldsA + swz((o_off + ln) * 128 + ks * 2 + hi * 16));
      s16x8 bf = *reinterpret_cast<const s16x8*>(ldsB + swz((t_off + ln) * 128 + ks * 2 + hi * 16));
      acc = __builtin_amdgcn_mfma_f32_32x32x16_bf16(af, bf, acc, 0, 0, 0);
    }
    __syncthreads();
  }

  size_t ybase = ((size_t)bp * 256 + o0) * 1024 + t0;
#pragma unroll
  for (int r = 0; r < 16; ++r) {
    int o = o_off + (r & 3) + 8 * (r >> 2) + 4 * hi;
    Y[ybase + (size_t)o * 1024 + t_off + ln] = acc[r] + bias[o0 + o];
  }
}

// per-group stats: mean = 4*sum(mb)/131072;
// E[out^2] = (sum(query^2) + sum(mb^2) - sum(qll^2)) / 131072
__global__ __launch_bounds__(256) void stats64_kernel(const float* __restrict__ mb,
    const unsigned short* __restrict__ qll, const float* __restrict__ partial,
    float* __restrict__ stats) {
  int g = blockIdx.x, tid = threadIdx.x;
  size_t base = (size_t)(g >> 5) * 262144 + (size_t)(g & 31) * 8192;
  const float4* p = reinterpret_cast<const float4*>(mb + base);
  float s = 0.f, s2 = 0.f;
  for (int e = tid; e < 2048; e += 256) {
    float4 v = p[e];
    s  += (v.x + v.y) + (v.z + v.w);
    s2 += (v.x * v.x + v.y * v.y) + (v.z * v.z + v.w * v.w);
  }
  const uint2* qp2 = reinterpret_cast<const uint2*>(qll + base);
  for (int e = tid; e < 2048; e += 256) {
    uint2 q = qp2[e];
    float a = bflo(q.x), b2 = bfhi(q.x), c2 = bflo(q.y), d2 = bfhi(q.y);
    s2 -= (a * a + b2 * b2) + (c2 * c2 + d2 * d2);
  }
  if (tid < 32) {
    int cc = tid >> 2, q = tid & 3;
    s2 += partial[(((g >> 5) * 256 + (g & 31) * 8 + cc) << 2) + q];
  }
  __shared__ float ls[256], ls2[256];
  ls[tid] = s; ls2[tid] = s2;
  __syncthreads();
  for (int off = 128; off > 0; off >>= 1) {
    if (tid < off) { ls[tid] += ls[tid + off]; ls2[tid] += ls2[tid + off]; }
    __syncthreads();
  }
  if (tid == 0) {
    float mean = 4.f * ls[0] * (1.f / 131072.f);
    float ex2  = ls2[0] * (1.f / 131072.f);
    float var  = ex2 - mean * mean;
    stats[g * 2]     = mean;
    stats[g * 2 + 1] = rsqrtf(var + 1e-5f);
  }
}

// out = GN(query + up4(0.25*(mb - qll))) + query, all in one streaming pass.
__global__ __launch_bounds__(256) void idwt_gn_kernel(const float* __restrict__ mb,
    const unsigned short* __restrict__ qll, const float* __restrict__ query,
    const float* __restrict__ stats, const float* __restrict__ gamma,
    const float* __restrict__ beta, float* __restrict__ out) {
  int idx = blockIdx.x * 256 + threadIdx.x;   // < 524288
  int bc = idx >> 10;
  int t  = idx & 1023;
  int i = t >> 5, j = t & 31;
  int c = bc & 255;
  int g = (bc >> 8) * 32 + (c >> 3);
  float mean = stats[2 * g], rstd = stats[2 * g + 1];
  float a_s = rstd * gamma[c];
  float be  = beta[c];
  float delta = 0.25f * (mb[idx] - bflo((unsigned)qll[idx]));
  float k1 = 1.f + a_s;
  float k2 = (delta - mean) * a_s + be;
  const float* qp = query + (size_t)bc * 16384;
  float* op = out + (size_t)bc * 16384;
#pragma unroll
  for (int rr = 0; rr < 4; ++rr) {
    int off = (4 * i + rr) * 128 + 4 * j;
    float4 q = *reinterpret_cast<const float4*>(qp + off);
    float4 o;
    o.x = q.x * k1 + k2;
    o.y = q.y * k1 + k2;
    o.z = q.z * k1 + k2;
    o.w = q.w * k1 + k2;
    *reinterpret_cast<float4*>(op + off) = o;
  }
}

extern "C" void kernel_launch(void* const* d_in, const int* in_sizes, int n_in,
                              void* d_out, int out_size, void* d_ws, size_t ws_size,
                              hipStream_t stream) {
  const float* query = (const float*)d_in[0];
  const float* kvm   = (const float*)d_in[1];
  // d_in[2] = value_multi: unused by the reference
  const float* Wq = (const float*)d_in[3];
  const float* bq = (const float*)d_in[4];
  const float* Wk = (const float*)d_in[5];
  const float* bk = (const float*)d_in[6];
  const float* Wv = (const float*)d_in[7];
  const float* bv = (const float*)d_in[8];
  const float* Wp = (const float*)d_in[9];
  const float* bp = (const float*)d_in[10];
  const float* gamma = (const float*)d_in[11];
  const float* beta  = (const float*)d_in[12];
  float* out = (float*)d_out;
  float* ws  = (float*)d_ws;

  if (ws_size < (size_t)5244032 * 4) return;  // insufficient scratch

  unsigned short* qll  = (unsigned short*)ws;            // 524288 us
  unsigned short* kvll = (unsigned short*)(ws + 262144); // 2097152 us
  unsigned*       qbp  = (unsigned*)(ws + 1310720);      // 262144 u32
  unsigned*       kbp  = (unsigned*)(ws + 1572864);      // 1048576 u32
  unsigned short* vb   = (unsigned short*)(ws + 2621440);// 2097152 us
  unsigned*       aop  = (unsigned*)(ws + 3670016);      // 1048576 u32
  float*          mb   = ws + 4718592;                   // 524288
  float*       partial = ws + 5242880;                   // 2048
  float*         stats = ws + 5244928 - 2048 + 2048;     // after partial
  stats = partial + 2048;                                // 128

  dwt_kernel<<<10240, 256, 0, stream>>>(query, kvm, qll, kvll, partial);

  conv_qkv_kernel<<<dim3(16, 4, 10), 256, 0, stream>>>(
      qll, kvll, Wq, bq, Wk, bk, Wv, bv, qbp, kbp, vb);

  attn_mfma_kernel<<<512, 256, 0, stream>>>(qbp, kbp, vb, aop);

  conv_pm_kernel<<<dim3(16, 4, 2), 256, 0, stream>>>(aop, Wp, bp, mb);
  stats64_kernel<<<64, 256, 0, stream>>>(mb, qll, partial, stats);

  idwt_gn_kernel<<<2048, 256, 0, stream>>>(mb, qll, query, stats,
                                           gamma, beta, out);
}